// Round 2
// baseline (1143.589 us; speedup 1.0000x reference)
//
#include <hip/hip_runtime.h>
#include <math.h>

#define S_LEN 1024
#define NHEAD 16
#define HDIM  64
#define BH    64           // B * NHEAD
#define NREL  257          // 2*128 + 1

// ---------------------------------------------------------------------------
// GEMM: C[r][c] = (sum_k A[r][k] * W[c][k] + bias[c]) * scale
//   A: [M][1024] row-major, W: [1024][1024] row-major (torch Linear weight)
// MODE 0: out[r*1024 + c]                         (plain [M][1024])
// MODE 1: out[((b*16+n)*1024 + s)*64 + d]         (QKV reshape to [B*nh][S][hd])
//         with b=r>>10, s=r&1023, n=c>>6, d=c&63
// Tile: BM=BN=64, BK=32, 256 threads, 4x4 micro-tile.
// LDS tiles stored K-major (transposed) with 68-float row stride so the
// inner-loop float4 reads are broadcast / 2-way at worst.
// ---------------------------------------------------------------------------
template<int MODE>
__global__ __launch_bounds__(256)
void gemm_xwt(const float* __restrict__ A, const float* __restrict__ W,
              const float* __restrict__ bias, float* __restrict__ out,
              float scale)
{
    __shared__ float As[32][68];
    __shared__ float Ws[32][68];
    const int tid  = threadIdx.x;
    const int tx   = tid & 15;        // 0..15 -> 4 cols each
    const int ty   = tid >> 4;        // 0..15 -> 4 rows each
    const int r0   = blockIdx.y << 6;
    const int c0   = blockIdx.x << 6;
    const int lrow = tid >> 3;        // 0..31
    const int lc4  = tid & 7;         // 0..7 (float4 column within 32 k's)

    float acc[4][4] = {{0.f,0.f,0.f,0.f},{0.f,0.f,0.f,0.f},
                       {0.f,0.f,0.f,0.f},{0.f,0.f,0.f,0.f}};

    for (int kt = 0; kt < 1024; kt += 32) {
        float4 a0 = *reinterpret_cast<const float4*>(&A[(size_t)(r0 + lrow)      * 1024 + kt + 4*lc4]);
        float4 a1 = *reinterpret_cast<const float4*>(&A[(size_t)(r0 + lrow + 32) * 1024 + kt + 4*lc4]);
        float4 w0 = *reinterpret_cast<const float4*>(&W[(size_t)(c0 + lrow)      * 1024 + kt + 4*lc4]);
        float4 w1 = *reinterpret_cast<const float4*>(&W[(size_t)(c0 + lrow + 32) * 1024 + kt + 4*lc4]);
        __syncthreads();   // previous iter's reads complete before overwrite
        As[4*lc4+0][lrow]    = a0.x; As[4*lc4+1][lrow]    = a0.y;
        As[4*lc4+2][lrow]    = a0.z; As[4*lc4+3][lrow]    = a0.w;
        As[4*lc4+0][lrow+32] = a1.x; As[4*lc4+1][lrow+32] = a1.y;
        As[4*lc4+2][lrow+32] = a1.z; As[4*lc4+3][lrow+32] = a1.w;
        Ws[4*lc4+0][lrow]    = w0.x; Ws[4*lc4+1][lrow]    = w0.y;
        Ws[4*lc4+2][lrow]    = w0.z; Ws[4*lc4+3][lrow]    = w0.w;
        Ws[4*lc4+0][lrow+32] = w1.x; Ws[4*lc4+1][lrow+32] = w1.y;
        Ws[4*lc4+2][lrow+32] = w1.z; Ws[4*lc4+3][lrow+32] = w1.w;
        __syncthreads();
        #pragma unroll
        for (int k = 0; k < 32; ++k) {
            float4 av = *reinterpret_cast<const float4*>(&As[k][4*ty]);
            float4 wv = *reinterpret_cast<const float4*>(&Ws[k][4*tx]);
            acc[0][0] += av.x*wv.x; acc[0][1] += av.x*wv.y; acc[0][2] += av.x*wv.z; acc[0][3] += av.x*wv.w;
            acc[1][0] += av.y*wv.x; acc[1][1] += av.y*wv.y; acc[1][2] += av.y*wv.z; acc[1][3] += av.y*wv.w;
            acc[2][0] += av.z*wv.x; acc[2][1] += av.z*wv.y; acc[2][2] += av.z*wv.z; acc[2][3] += av.z*wv.w;
            acc[3][0] += av.w*wv.x; acc[3][1] += av.w*wv.y; acc[3][2] += av.w*wv.z; acc[3][3] += av.w*wv.w;
        }
    }

    float4 bv = *reinterpret_cast<const float4*>(&bias[c0 + 4*tx]);
    #pragma unroll
    for (int i = 0; i < 4; ++i) {
        const int r = r0 + 4*ty + i;
        float4 res;
        res.x = (acc[i][0] + bv.x) * scale;
        res.y = (acc[i][1] + bv.y) * scale;
        res.z = (acc[i][2] + bv.z) * scale;
        res.w = (acc[i][3] + bv.w) * scale;
        if (MODE == 0) {
            *reinterpret_cast<float4*>(&out[(size_t)r * 1024 + c0 + 4*tx]) = res;
        } else {
            const int b = r >> 10, s = r & 1023, n = c0 >> 6;
            const size_t base = ((((size_t)(b*16 + n) << 10) | (size_t)s) << 6) + 4*tx;
            *reinterpret_cast<float4*>(&out[base]) = res;
        }
    }
}

// ---------------------------------------------------------------------------
// Qrel[bh][s][r] = dot(Q[bh][s][:], rel_emb[r][:])   r in 0..256
// Q is prescaled by 1/sqrt(hd), so Qrel carries the scale too.
// Block: 320 threads; handles one bh x 32 s-rows; thread r owns one rel row
// (64 floats in regs), loops s reading Q from LDS (pure broadcast).
// ---------------------------------------------------------------------------
__global__ __launch_bounds__(320)
void qrel_kernel(const float* __restrict__ Q, const float* __restrict__ rel,
                 float* __restrict__ qrel)
{
    __shared__ float Qs[32][64];
    const int bh = blockIdx.y;
    const int s0 = blockIdx.x << 5;
    const float* qbase = Q + ((size_t)bh * S_LEN + s0) * HDIM;
    for (int i = threadIdx.x; i < 32*64; i += 320)
        Qs[i >> 6][i & 63] = qbase[i];
    __syncthreads();

    const int r = threadIdx.x;
    if (r < NREL) {
        float4 e[16];
        #pragma unroll
        for (int j = 0; j < 16; ++j)
            e[j] = *reinterpret_cast<const float4*>(&rel[(size_t)r * 64 + 4*j]);
        float* orow = qrel + ((size_t)bh * S_LEN + s0) * NREL + r;
        for (int s = 0; s < 32; ++s) {
            float acc = 0.f;
            #pragma unroll
            for (int j = 0; j < 16; ++j) {
                float4 q4 = *reinterpret_cast<const float4*>(&Qs[s][4*j]);
                acc += q4.x*e[j].x + q4.y*e[j].y + q4.z*e[j].z + q4.w*e[j].w;
            }
            orow[(size_t)s * NREL] = acc;
        }
    }
}

// ---------------------------------------------------------------------------
// Flash attention (fp32): block = (q-tile of 32 rows) x (one bh).
// 4 waves; wave w owns q rows w*8..w*8+7; within a wave, lane l:
//   q = w*8 + (l>>3),  k-slot m = l&7 (k = m+8j, j=0..7),  d-slice = m*8..m*8+7
// Q row (prescaled by 1/8) held in 16 float4 regs. K/V tiles (64 rows) staged
// in LDS. Online softmax stats duplicated across the 8 lanes of a q-group
// (consistent after shfl reductions).
// ---------------------------------------------------------------------------
__global__ __launch_bounds__(256)
void attn_kernel(const float* __restrict__ Q, const float* __restrict__ K,
                 const float* __restrict__ V, const float* __restrict__ qrel,
                 float* __restrict__ AO)
{
    __shared__ float Ks[64][68];
    __shared__ float Vs[64][68];
    __shared__ float Ps[32][68];

    const int bh = blockIdx.y;
    const int q0 = blockIdx.x << 5;
    const int tid = threadIdx.x;
    const int w  = tid >> 6;
    const int l  = tid & 63;
    const int qg = l >> 3;
    const int m8 = l & 7;
    const int q  = w*8 + qg;           // local q row 0..31
    const int qglob = q0 + q;

    float4 qreg[16];
    {
        const float* qrow = Q + ((size_t)bh * S_LEN + qglob) * HDIM;
        #pragma unroll
        for (int j = 0; j < 16; ++j)
            qreg[j] = *reinterpret_cast<const float4*>(&qrow[4*j]);
    }
    const float* qrl = qrel + ((size_t)bh * S_LEN + qglob) * NREL;

    float m_run = -1e30f, l_run = 0.f;
    float o[8] = {0.f,0.f,0.f,0.f,0.f,0.f,0.f,0.f};

    const int lr = tid >> 2;   // 0..63  (K/V staging row)
    const int lc = tid & 3;    // 0..3

    for (int kt = 0; kt < S_LEN; kt += 64) {
        __syncthreads();   // prior-iter Ks/Vs/Ps reads done
        #pragma unroll
        for (int i = 0; i < 4; ++i) {
            const int c4 = lc + 4*i;
            float4 kv = *reinterpret_cast<const float4*>(&K[(((size_t)bh << 10) + kt + lr) * 64 + 4*c4]);
            float4 vv = *reinterpret_cast<const float4*>(&V[(((size_t)bh << 10) + kt + lr) * 64 + 4*c4]);
            *reinterpret_cast<float4*>(&Ks[lr][4*c4]) = kv;
            *reinterpret_cast<float4*>(&Vs[lr][4*c4]) = vv;
        }
        __syncthreads();

        // ---- scores for this lane's 8 k's
        float p[8];
        float tmax = -1e30f;
        #pragma unroll
        for (int j = 0; j < 8; ++j) {
            const int k = m8 + 8*j;
            float s4 = 0.f;
            #pragma unroll
            for (int dd = 0; dd < 16; ++dd) {
                float4 k4 = *reinterpret_cast<const float4*>(&Ks[k][4*dd]);
                s4 += qreg[dd].x*k4.x + qreg[dd].y*k4.y + qreg[dd].z*k4.z + qreg[dd].w*k4.w;
            }
            int d = kt + k - qglob;
            d = (d < -128) ? -128 : ((d > 128) ? 128 : d);
            s4 += qrl[d + 128];
            p[j] = s4;
            tmax = fmaxf(tmax, s4);
        }
        // ---- reduce max/sum over the 8 lanes of the q-group
        tmax = fmaxf(tmax, __shfl_xor(tmax, 1));
        tmax = fmaxf(tmax, __shfl_xor(tmax, 2));
        tmax = fmaxf(tmax, __shfl_xor(tmax, 4));
        const float m_new = fmaxf(m_run, tmax);
        const float corr  = __expf(m_run - m_new);
        float psum = 0.f;
        #pragma unroll
        for (int j = 0; j < 8; ++j) { p[j] = __expf(p[j] - m_new); psum += p[j]; }
        psum += __shfl_xor(psum, 1);
        psum += __shfl_xor(psum, 2);
        psum += __shfl_xor(psum, 4);
        l_run = l_run * corr + psum;
        m_run = m_new;
        #pragma unroll
        for (int i = 0; i < 8; ++i) o[i] *= corr;

        #pragma unroll
        for (int j = 0; j < 8; ++j) Ps[q][m8 + 8*j] = p[j];
        __syncthreads();

        // ---- PV: lane accumulates its 8-wide d-slice for its q row
        #pragma unroll
        for (int k = 0; k < 64; ++k) {
            const float pk = Ps[q][k];
            float4 v0 = *reinterpret_cast<const float4*>(&Vs[k][m8*8]);
            float4 v1 = *reinterpret_cast<const float4*>(&Vs[k][m8*8 + 4]);
            o[0] += pk*v0.x; o[1] += pk*v0.y; o[2] += pk*v0.z; o[3] += pk*v0.w;
            o[4] += pk*v1.x; o[5] += pk*v1.y; o[6] += pk*v1.z; o[7] += pk*v1.w;
        }
    }

    const float inv = 1.f / l_run;
    #pragma unroll
    for (int i = 0; i < 8; ++i) o[i] *= inv;

    // AO is [B][S][H]: b = bh>>4, n = bh&15, h = n*64 + m8*8 + i
    float* dst = AO + (((size_t)(bh >> 4) * S_LEN + qglob) * 1024) + (bh & 15) * 64 + m8*8;
    float4 o0 = {o[0], o[1], o[2], o[3]};
    float4 o1 = {o[4], o[5], o[6], o[7]};
    *reinterpret_cast<float4*>(dst)     = o0;
    *reinterpret_cast<float4*>(dst + 4) = o1;
}

// ---------------------------------------------------------------------------
extern "C" void kernel_launch(void* const* d_in, const int* in_sizes, int n_in,
                              void* d_out, int out_size, void* d_ws, size_t ws_size,
                              hipStream_t stream)
{
    const float* x   = (const float*)d_in[0];
    const float* Wq  = (const float*)d_in[1];
    const float* bq  = (const float*)d_in[2];
    const float* Wk  = (const float*)d_in[3];
    const float* bk  = (const float*)d_in[4];
    const float* Wv  = (const float*)d_in[5];
    const float* bv  = (const float*)d_in[6];
    const float* Wo  = (const float*)d_in[7];
    const float* bo  = (const float*)d_in[8];
    const float* rel = (const float*)d_in[9];
    float* out = (float*)d_out;

    // workspace layout (floats): Q | K | V | QREL | AO   = 134.5 MB total
    float* ws = (float*)d_ws;
    const size_t QKV = (size_t)BH * S_LEN * HDIM;       // 4,194,304
    float* Qb = ws;
    float* Kb = Qb + QKV;
    float* Vb = Kb + QKV;
    float* QR = Vb + QKV;                               // BH*S*257
    float* AO = QR + (size_t)BH * S_LEN * NREL;

    dim3 gg(16, 64), gb(256);
    // Q prescaled by 1/sqrt(hd)=0.125 (both score terms are linear in Q)
    gemm_xwt<1><<<gg, gb, 0, stream>>>(x, Wq, bq, Qb, 0.125f);
    gemm_xwt<1><<<gg, gb, 0, stream>>>(x, Wk, bk, Kb, 1.0f);
    gemm_xwt<1><<<gg, gb, 0, stream>>>(x, Wv, bv, Vb, 1.0f);

    qrel_kernel<<<dim3(32, 64), dim3(320), 0, stream>>>(Qb, rel, QR);

    attn_kernel<<<dim3(32, 64), dim3(256), 0, stream>>>(Qb, Kb, Vb, QR, AO);

    gemm_xwt<0><<<gg, gb, 0, stream>>>(AO, Wo, bo, out, 1.0f);
}

// Round 3
// 824.458 us; speedup vs baseline: 1.3871x; 1.3871x over previous
//
#include <hip/hip_runtime.h>
#include <math.h>

#define S_LEN 1024
#define NHEAD 16
#define HDIM  64
#define BH    64           // B * NHEAD
#define NREL  257          // 2*128 + 1

typedef unsigned short ushort_t;
typedef __attribute__((ext_vector_type(8))) short bf16x8;
typedef __attribute__((ext_vector_type(4))) float f32x4;

__device__ inline ushort_t f2bf(float f) {
    unsigned u = __float_as_uint(f);
    unsigned r = u + 0x7FFFu + ((u >> 16) & 1u);   // RNE
    return (ushort_t)(r >> 16);
}
__device__ inline float bf2f(ushort_t h) {
    return __uint_as_float(((unsigned)h) << 16);
}

__device__ inline void load_lds_16(const void* g, void* l) {
    __builtin_amdgcn_global_load_lds(
        (const __attribute__((address_space(1))) void*)g,
        (__attribute__((address_space(3))) void*)l, 16, 0, 0);
}

// ---------------------------------------------------------------------------
// Split fp32 [R][1024] (row-major) into hi/lo bf16 in TILED layout:
//   chunk t (16B = 8 bf16):  t = ((mtile*32 + ktile)*4 + kc)*128 + row128
//   source element = src[(mtile*128+row128)*1024 + ktile*32 + kc*8 + i]
// One thread per chunk. grid = R*128/256.
// ---------------------------------------------------------------------------
__global__ __launch_bounds__(256)
void convert_split(const float* __restrict__ src, ushort_t* __restrict__ hi,
                   ushort_t* __restrict__ lo)
{
    const int t = blockIdx.x * 256 + threadIdx.x;
    const int row128 = t & 127;
    const int kc     = (t >> 7) & 3;
    const int ktile  = (t >> 9) & 31;
    const int mtile  = t >> 14;
    const float* s = src + ((size_t)(mtile * 128 + row128) * 1024) + ktile * 32 + kc * 8;
    float4 v0 = *reinterpret_cast<const float4*>(s);
    float4 v1 = *reinterpret_cast<const float4*>(s + 4);
    float v[8] = {v0.x, v0.y, v0.z, v0.w, v1.x, v1.y, v1.z, v1.w};
    union { ushort_t u[8]; int4 q; } H, L;
    #pragma unroll
    for (int i = 0; i < 8; ++i) {
        ushort_t h = f2bf(v[i]);
        H.u[i] = h;
        L.u[i] = f2bf(v[i] - bf2f(h));
    }
    reinterpret_cast<int4*>(hi)[t] = H.q;
    reinterpret_cast<int4*>(lo)[t] = L.q;
}

// ---------------------------------------------------------------------------
// Split-bf16 MFMA GEMM: C[r][c] = (sum_k A[r][k]*W[c][k] + bias[c]) * scale
// A: tiled hi/lo [M/128][32][4][128][8], W: tiled hi/lo [8][32][4][128][8]
// 128x128 tile, BK=32, 256 thr / 4 waves, each wave 64x64 (4x4 frags of
// 16x16x32). 3 MFMA passes: hh + hl + lh. Double-buffered LDS (2x32KB),
// T3-minimum 2-phase: stage(t+1) issued before compute(t), one barrier/tile.
// MODE 0: out[r*1024+c];  MODE 1: QKV layout out[((b*16+n)*1024+s)*64+d]
// ---------------------------------------------------------------------------
template<int MODE>
__global__ __launch_bounds__(256)
void gemm_split(const ushort_t* __restrict__ Ah, const ushort_t* __restrict__ Al,
                const ushort_t* __restrict__ Bh, const ushort_t* __restrict__ Bl,
                const float* __restrict__ bias, float* __restrict__ out, float scale)
{
    __shared__ __align__(16) short sm[2][4][4096];   // [buf][Ah,Al,Bh,Bl][8KB]
    const int tid  = threadIdx.x;
    const int wave = tid >> 6, lane = tid & 63;
    const int wm = wave >> 1, wn = wave & 1;
    const int r16 = lane & 15, kq = lane >> 4;       // frag row / k-quarter
    const int mtile = blockIdx.y;
    const int ntile = blockIdx.x;
    const int wb = (tid & ~63) << 3;                 // wave-uniform LDS ushort offset

    f32x4 acc[4][4] = {};

    auto stage = [&](int buf, int kt) {
        const ushort_t* g[4] = {
            Ah + ((size_t)(mtile * 32 + kt) << 12),
            Al + ((size_t)(mtile * 32 + kt) << 12),
            Bh + ((size_t)(ntile * 32 + kt) << 12),
            Bl + ((size_t)(ntile * 32 + kt) << 12)};
        #pragma unroll
        for (int t4 = 0; t4 < 4; ++t4) {
            load_lds_16(g[t4] + ((size_t)tid << 3),         &sm[buf][t4][wb]);
            load_lds_16(g[t4] + ((size_t)(tid + 256) << 3), &sm[buf][t4][wb + 2048]);
        }
    };

    stage(0, 0);
    __syncthreads();

    for (int kt = 0; kt < 32; ++kt) {
        const int cur = kt & 1;
        if (kt + 1 < 32) stage(cur ^ 1, kt + 1);

        const bf16x8* pAh = reinterpret_cast<const bf16x8*>(sm[cur][0]);
        const bf16x8* pAl = reinterpret_cast<const bf16x8*>(sm[cur][1]);
        const bf16x8* pBh = reinterpret_cast<const bf16x8*>(sm[cur][2]);
        const bf16x8* pBl = reinterpret_cast<const bf16x8*>(sm[cur][3]);

        bf16x8 afh[4], afl[4], bfh[4], bfl[4];
        #pragma unroll
        for (int m = 0; m < 4; ++m) {
            const int ch = kq * 128 + wm * 64 + m * 16 + r16;
            afh[m] = pAh[ch]; afl[m] = pAl[ch];
        }
        #pragma unroll
        for (int n = 0; n < 4; ++n) {
            const int ch = kq * 128 + wn * 64 + n * 16 + r16;
            bfh[n] = pBh[ch]; bfl[n] = pBl[ch];
        }
        #pragma unroll
        for (int m = 0; m < 4; ++m)
            #pragma unroll
            for (int n = 0; n < 4; ++n) {
                acc[m][n] = __builtin_amdgcn_mfma_f32_16x16x32_bf16(afh[m], bfh[n], acc[m][n], 0, 0, 0);
                acc[m][n] = __builtin_amdgcn_mfma_f32_16x16x32_bf16(afh[m], bfl[n], acc[m][n], 0, 0, 0);
                acc[m][n] = __builtin_amdgcn_mfma_f32_16x16x32_bf16(afl[m], bfh[n], acc[m][n], 0, 0, 0);
            }
        __syncthreads();   // drains vmcnt (stage done) + all waves done reading cur
    }

    const int row0 = (mtile << 7) + wm * 64;
    const int col0 = (ntile << 7) + wn * 64;
    #pragma unroll
    for (int n = 0; n < 4; ++n) {
        const int col = col0 + n * 16 + r16;
        const float bc = bias[col];
        #pragma unroll
        for (int m = 0; m < 4; ++m) {
            #pragma unroll
            for (int r = 0; r < 4; ++r) {
                const int row = row0 + m * 16 + kq * 4 + r;
                const float val = (acc[m][n][r] + bc) * scale;
                if (MODE == 0) {
                    out[(size_t)row * 1024 + col] = val;
                } else {
                    const int b = row >> 10, s = row & 1023;
                    const int nh = col >> 6, d = col & 63;
                    out[((((size_t)(b * 16 + nh)) << 10 | (size_t)s) << 6) + d] = val;
                }
            }
        }
    }
}

// ---------------------------------------------------------------------------
// Qrel[bh][s][r] = dot(Q[bh][s][:], rel_emb[r][:]) -> bf16
// ---------------------------------------------------------------------------
__global__ __launch_bounds__(320)
void qrel_kernel(const float* __restrict__ Q, const float* __restrict__ rel,
                 ushort_t* __restrict__ qrel)
{
    __shared__ float Qs[32][64];
    const int bh = blockIdx.y;
    const int s0 = blockIdx.x << 5;
    const float* qbase = Q + ((size_t)bh * S_LEN + s0) * HDIM;
    for (int i = threadIdx.x; i < 32 * 64; i += 320)
        Qs[i >> 6][i & 63] = qbase[i];
    __syncthreads();

    const int r = threadIdx.x;
    if (r < NREL) {
        float4 e[16];
        #pragma unroll
        for (int j = 0; j < 16; ++j)
            e[j] = *reinterpret_cast<const float4*>(&rel[(size_t)r * 64 + 4 * j]);
        ushort_t* orow = qrel + ((size_t)bh * S_LEN + s0) * NREL + r;
        for (int s = 0; s < 32; ++s) {
            float acc = 0.f;
            #pragma unroll
            for (int j = 0; j < 16; ++j) {
                float4 q4 = *reinterpret_cast<const float4*>(&Qs[s][4 * j]);
                acc += q4.x*e[j].x + q4.y*e[j].y + q4.z*e[j].z + q4.w*e[j].w;
            }
            orow[(size_t)s * NREL] = f2bf(acc);
        }
    }
}

// ---------------------------------------------------------------------------
// Flash attention (fp32 compute). Output written DIRECTLY as tiled hi/lo bf16
// (the final GEMM's A-operand layout): each lane's 8-float d-slice is exactly
// one 16B chunk.
// ---------------------------------------------------------------------------
__global__ __launch_bounds__(256)
void attn_kernel(const float* __restrict__ Q, const float* __restrict__ K,
                 const float* __restrict__ V, const ushort_t* __restrict__ qrel,
                 ushort_t* __restrict__ AOh, ushort_t* __restrict__ AOl)
{
    __shared__ float Ks[64][68];
    __shared__ float Vs[64][68];
    __shared__ float Ps[32][68];

    const int bh = blockIdx.y;
    const int q0 = blockIdx.x << 5;
    const int tid = threadIdx.x;
    const int w  = tid >> 6;
    const int l  = tid & 63;
    const int qg = l >> 3;
    const int m8 = l & 7;
    const int q  = w * 8 + qg;
    const int qglob = q0 + q;

    float4 qreg[16];
    {
        const float* qrow = Q + ((size_t)bh * S_LEN + qglob) * HDIM;
        #pragma unroll
        for (int j = 0; j < 16; ++j)
            qreg[j] = *reinterpret_cast<const float4*>(&qrow[4 * j]);
    }
    const ushort_t* qrl = qrel + ((size_t)bh * S_LEN + qglob) * NREL;

    float m_run = -1e30f, l_run = 0.f;
    float o[8] = {0.f,0.f,0.f,0.f,0.f,0.f,0.f,0.f};

    const int lr = tid >> 2;
    const int lc = tid & 3;

    for (int kt = 0; kt < S_LEN; kt += 64) {
        __syncthreads();
        #pragma unroll
        for (int i = 0; i < 4; ++i) {
            const int c4 = lc + 4 * i;
            float4 kv = *reinterpret_cast<const float4*>(&K[(((size_t)bh << 10) + kt + lr) * 64 + 4 * c4]);
            float4 vv = *reinterpret_cast<const float4*>(&V[(((size_t)bh << 10) + kt + lr) * 64 + 4 * c4]);
            *reinterpret_cast<float4*>(&Ks[lr][4 * c4]) = kv;
            *reinterpret_cast<float4*>(&Vs[lr][4 * c4]) = vv;
        }
        __syncthreads();

        float p[8];
        float tmax = -1e30f;
        #pragma unroll
        for (int j = 0; j < 8; ++j) {
            const int k = m8 + 8 * j;
            float s4 = 0.f;
            #pragma unroll
            for (int dd = 0; dd < 16; ++dd) {
                float4 k4 = *reinterpret_cast<const float4*>(&Ks[k][4 * dd]);
                s4 += qreg[dd].x*k4.x + qreg[dd].y*k4.y + qreg[dd].z*k4.z + qreg[dd].w*k4.w;
            }
            int d = kt + k - qglob;
            d = (d < -128) ? -128 : ((d > 128) ? 128 : d);
            s4 += bf2f(qrl[d + 128]);
            p[j] = s4;
            tmax = fmaxf(tmax, s4);
        }
        tmax = fmaxf(tmax, __shfl_xor(tmax, 1));
        tmax = fmaxf(tmax, __shfl_xor(tmax, 2));
        tmax = fmaxf(tmax, __shfl_xor(tmax, 4));
        const float m_new = fmaxf(m_run, tmax);
        const float corr  = __expf(m_run - m_new);
        float psum = 0.f;
        #pragma unroll
        for (int j = 0; j < 8; ++j) { p[j] = __expf(p[j] - m_new); psum += p[j]; }
        psum += __shfl_xor(psum, 1);
        psum += __shfl_xor(psum, 2);
        psum += __shfl_xor(psum, 4);
        l_run = l_run * corr + psum;
        m_run = m_new;
        #pragma unroll
        for (int i = 0; i < 8; ++i) o[i] *= corr;

        #pragma unroll
        for (int j = 0; j < 8; ++j) Ps[q][m8 + 8 * j] = p[j];
        __syncthreads();

        #pragma unroll
        for (int k = 0; k < 64; ++k) {
            const float pk = Ps[q][k];
            float4 v0 = *reinterpret_cast<const float4*>(&Vs[k][m8 * 8]);
            float4 v1 = *reinterpret_cast<const float4*>(&Vs[k][m8 * 8 + 4]);
            o[0] += pk*v0.x; o[1] += pk*v0.y; o[2] += pk*v0.z; o[3] += pk*v0.w;
            o[4] += pk*v1.x; o[5] += pk*v1.y; o[6] += pk*v1.z; o[7] += pk*v1.w;
        }
    }

    const float inv = 1.f / l_run;
    union { ushort_t u[8]; int4 q4; } H, L;
    #pragma unroll
    for (int i = 0; i < 8; ++i) {
        const float v = o[i] * inv;
        const ushort_t h = f2bf(v);
        H.u[i] = h;
        L.u[i] = f2bf(v - bf2f(h));
    }
    // tiled chunk: r = b*1024 + s ; k = nh*64 + m8*8
    const int r_glob = ((bh >> 4) << 10) + qglob;
    const int k      = ((bh & 15) << 6) + m8 * 8;
    const int mtile = r_glob >> 7, row128 = r_glob & 127;
    const int ktile = k >> 5,      kc     = (k >> 3) & 3;
    const size_t chunk = ((size_t)(mtile * 32 + ktile) * 4 + kc) * 128 + row128;
    reinterpret_cast<int4*>(AOh)[chunk] = H.q4;
    reinterpret_cast<int4*>(AOl)[chunk] = L.q4;
}

// ---------------------------------------------------------------------------
extern "C" void kernel_launch(void* const* d_in, const int* in_sizes, int n_in,
                              void* d_out, int out_size, void* d_ws, size_t ws_size,
                              hipStream_t stream)
{
    const float* x   = (const float*)d_in[0];
    const float* Wq  = (const float*)d_in[1];
    const float* bq  = (const float*)d_in[2];
    const float* Wk  = (const float*)d_in[3];
    const float* bk  = (const float*)d_in[4];
    const float* Wv  = (const float*)d_in[5];
    const float* bv  = (const float*)d_in[6];
    const float* Wo  = (const float*)d_in[7];
    const float* bo  = (const float*)d_in[8];
    const float* rel = (const float*)d_in[9];
    float* out = (float*)d_out;

    // workspace layout (bytes), total 134,348,800 B (fits proven 134.5 MB):
    char* W = (char*)d_ws;
    float*    Qb  = (float*)   (W);                 // 16 MB
    float*    Kb  = (float*)   (W + 16777216);      // 16 MB
    float*    Vb  = (float*)   (W + 33554432);      // 16 MB
    ushort_t* QR  = (ushort_t*)(W + 50331648);      // 33,685,504 B (bf16)
    ushort_t* xh  = (ushort_t*)(W + 84017152);      // 8 MB
    ushort_t* xl  = (ushort_t*)(W + 92405760);      // 8 MB
    ushort_t* wqh = (ushort_t*)(W + 100794368);     // 2 MB each
    ushort_t* wkh = (ushort_t*)(W + 102891520);
    ushort_t* wvh = (ushort_t*)(W + 104988672);
    ushort_t* woh = (ushort_t*)(W + 107085824);
    ushort_t* wql = (ushort_t*)(W + 109182976);
    ushort_t* wkl = (ushort_t*)(W + 111280128);
    ushort_t* wvl = (ushort_t*)(W + 113377280);
    ushort_t* wol = (ushort_t*)(W + 115474432);
    ushort_t* AOh = (ushort_t*)(W + 117571584);     // 8 MB
    ushort_t* AOl = (ushort_t*)(W + 125960192);     // 8 MB

    convert_split<<<2048, 256, 0, stream>>>(x,  xh,  xl);
    convert_split<<<512,  256, 0, stream>>>(Wq, wqh, wql);
    convert_split<<<512,  256, 0, stream>>>(Wk, wkh, wkl);
    convert_split<<<512,  256, 0, stream>>>(Wv, wvh, wvl);
    convert_split<<<512,  256, 0, stream>>>(Wo, woh, wol);

    dim3 gg(8, 32), gb(256);
    gemm_split<1><<<gg, gb, 0, stream>>>(xh, xl, wqh, wql, bq, Qb, 0.125f);
    gemm_split<1><<<gg, gb, 0, stream>>>(xh, xl, wkh, wkl, bk, Kb, 1.0f);
    gemm_split<1><<<gg, gb, 0, stream>>>(xh, xl, wvh, wvl, bv, Vb, 1.0f);

    qrel_kernel<<<dim3(32, 64), dim3(320), 0, stream>>>(Qb, rel, QR);

    attn_kernel<<<dim3(32, 64), dim3(256), 0, stream>>>(Qb, Kb, Vb, QR, AOh, AOl);

    gemm_split<0><<<gg, gb, 0, stream>>>(AOh, AOl, woh, wol, bo, out, 1.0f);
}

// Round 4
// 466.347 us; speedup vs baseline: 2.4522x; 1.7679x over previous
//
#include <hip/hip_runtime.h>
#include <math.h>

#define S_LEN 1024
#define NREL  257

typedef unsigned short ushort_t;
typedef __attribute__((ext_vector_type(8))) short bf16x8;
typedef __attribute__((ext_vector_type(4))) float f32x4;

__device__ inline ushort_t f2bf(float f) {
    unsigned u = __float_as_uint(f);
    unsigned r = u + 0x7FFFu + ((u >> 16) & 1u);   // RNE
    return (ushort_t)(r >> 16);
}
__device__ inline float bf2f(ushort_t h) {
    return __uint_as_float(((unsigned)h) << 16);
}

__device__ inline void load_lds_16(const void* g, void* l) {
    __builtin_amdgcn_global_load_lds(
        (const __attribute__((address_space(1))) void*)g,
        (__attribute__((address_space(3))) void*)l, 16, 0, 0);
}

// ---------------------------------------------------------------------------
// Split fp32 [R][1024] into hi/lo bf16 GEMM-operand tiles:
//   chunk t: t = ((mtile*32 + ktile)*4 + kc)*128 + row128
// ---------------------------------------------------------------------------
__global__ __launch_bounds__(256)
void convert_split(const float* __restrict__ src, ushort_t* __restrict__ hi,
                   ushort_t* __restrict__ lo)
{
    const int t = blockIdx.x * 256 + threadIdx.x;
    const int row128 = t & 127;
    const int kc     = (t >> 7) & 3;
    const int ktile  = (t >> 9) & 31;
    const int mtile  = t >> 14;
    const float* s = src + ((size_t)(mtile * 128 + row128) * 1024) + ktile * 32 + kc * 8;
    float4 v0 = *reinterpret_cast<const float4*>(s);
    float4 v1 = *reinterpret_cast<const float4*>(s + 4);
    float v[8] = {v0.x, v0.y, v0.z, v0.w, v1.x, v1.y, v1.z, v1.w};
    union { ushort_t u[8]; int4 q; } H, L;
    #pragma unroll
    for (int i = 0; i < 8; ++i) {
        ushort_t h = f2bf(v[i]);
        H.u[i] = h;
        L.u[i] = f2bf(v[i] - bf2f(h));
    }
    reinterpret_cast<int4*>(hi)[t] = H.q;
    reinterpret_cast<int4*>(lo)[t] = L.q;
}

// ---------------------------------------------------------------------------
// Split-bf16 MFMA GEMM. 128x128 tile, BK=32, 4 waves, 3 MFMA passes (hh,hl,lh)
// Epilogue MODE:
//  0: fp32 out[r*1024 + c]
//  1: fp32 QKV out[((b*16+nh)*1024+s)*64+d]
//  2: K attn-tiled hi/lo bf16: chunk = bh*8192 + (s>>6)*512 + (d>>3)*64 + (s&63), elem d&7
//  3: V^T attn-tiled hi bf16:  chunk = bh*8192 + (s>>6)*512 + ((s&63)>>3)*64 + d, elem s&7
// ---------------------------------------------------------------------------
template<int MODE>
__global__ __launch_bounds__(256)
void gemm_split(const ushort_t* __restrict__ Ah, const ushort_t* __restrict__ Al,
                const ushort_t* __restrict__ Bh, const ushort_t* __restrict__ Bl,
                const float* __restrict__ bias, float* __restrict__ out,
                ushort_t* __restrict__ ohi, ushort_t* __restrict__ olo, float scale)
{
    __shared__ __align__(16) short sm[2][4][4096];
    const int tid  = threadIdx.x;
    const int wave = tid >> 6, lane = tid & 63;
    const int wm = wave >> 1, wn = wave & 1;
    const int r16 = lane & 15, kq = lane >> 4;
    const int mtile = blockIdx.y;
    const int ntile = blockIdx.x;
    const int wb = (tid & ~63) << 3;

    f32x4 acc[4][4] = {};

    auto stage = [&](int buf, int kt) {
        const ushort_t* g[4] = {
            Ah + ((size_t)(mtile * 32 + kt) << 12),
            Al + ((size_t)(mtile * 32 + kt) << 12),
            Bh + ((size_t)(ntile * 32 + kt) << 12),
            Bl + ((size_t)(ntile * 32 + kt) << 12)};
        #pragma unroll
        for (int t4 = 0; t4 < 4; ++t4) {
            load_lds_16(g[t4] + ((size_t)tid << 3),         &sm[buf][t4][wb]);
            load_lds_16(g[t4] + ((size_t)(tid + 256) << 3), &sm[buf][t4][wb + 2048]);
        }
    };

    stage(0, 0);
    __syncthreads();

    for (int kt = 0; kt < 32; ++kt) {
        const int cur = kt & 1;
        if (kt + 1 < 32) stage(cur ^ 1, kt + 1);

        const bf16x8* pAh = reinterpret_cast<const bf16x8*>(sm[cur][0]);
        const bf16x8* pAl = reinterpret_cast<const bf16x8*>(sm[cur][1]);
        const bf16x8* pBh = reinterpret_cast<const bf16x8*>(sm[cur][2]);
        const bf16x8* pBl = reinterpret_cast<const bf16x8*>(sm[cur][3]);

        bf16x8 afh[4], afl[4], bfh[4], bfl[4];
        #pragma unroll
        for (int m = 0; m < 4; ++m) {
            const int ch = kq * 128 + wm * 64 + m * 16 + r16;
            afh[m] = pAh[ch]; afl[m] = pAl[ch];
        }
        #pragma unroll
        for (int n = 0; n < 4; ++n) {
            const int ch = kq * 128 + wn * 64 + n * 16 + r16;
            bfh[n] = pBh[ch]; bfl[n] = pBl[ch];
        }
        #pragma unroll
        for (int m = 0; m < 4; ++m)
            #pragma unroll
            for (int n = 0; n < 4; ++n) {
                acc[m][n] = __builtin_amdgcn_mfma_f32_16x16x32_bf16(afh[m], bfh[n], acc[m][n], 0, 0, 0);
                acc[m][n] = __builtin_amdgcn_mfma_f32_16x16x32_bf16(afh[m], bfl[n], acc[m][n], 0, 0, 0);
                acc[m][n] = __builtin_amdgcn_mfma_f32_16x16x32_bf16(afl[m], bfh[n], acc[m][n], 0, 0, 0);
            }
        __syncthreads();
    }

    const int row0 = (mtile << 7) + wm * 64;
    const int col0 = (ntile << 7) + wn * 64;
    #pragma unroll
    for (int n = 0; n < 4; ++n) {
        const int col = col0 + n * 16 + r16;
        const float bc = bias[col];
        #pragma unroll
        for (int m = 0; m < 4; ++m) {
            #pragma unroll
            for (int r = 0; r < 4; ++r) {
                const int row = row0 + m * 16 + kq * 4 + r;
                const float val = (acc[m][n][r] + bc) * scale;
                if (MODE == 0) {
                    out[(size_t)row * 1024 + col] = val;
                } else if (MODE == 1) {
                    const int b = row >> 10, s = row & 1023;
                    const int nh = col >> 6, d = col & 63;
                    out[((((size_t)(b * 16 + nh)) << 10 | (size_t)s) << 6) + d] = val;
                } else if (MODE == 2) {
                    const int b = row >> 10, s = row & 1023;
                    const int nh = col >> 6, d = col & 63;
                    const size_t cidx = (((size_t)(b * 16 + nh) << 13) + ((s >> 6) << 9)
                                        + ((d >> 3) << 6) + (s & 63)) * 8 + (d & 7);
                    const ushort_t h = f2bf(val);
                    ohi[cidx] = h;
                    olo[cidx] = f2bf(val - bf2f(h));
                } else {  // MODE 3: V^T
                    const int b = row >> 10, s = row & 1023;
                    const int nh = col >> 6, d = col & 63;
                    const int kk = s & 63;
                    const size_t cidx = (((size_t)(b * 16 + nh) << 13) + ((s >> 6) << 9)
                                        + ((kk >> 3) << 6) + d) * 8 + (kk & 7);
                    ohi[cidx] = f2bf(val);
                }
            }
        }
    }
}

// ---------------------------------------------------------------------------
// Qrel[bh][s][r] = dot(Q[bh][s][:], rel_emb[r][:]) -> bf16
// ---------------------------------------------------------------------------
__global__ __launch_bounds__(320)
void qrel_kernel(const float* __restrict__ Q, const float* __restrict__ rel,
                 ushort_t* __restrict__ qrel)
{
    __shared__ float Qs[32][64];
    const int bh = blockIdx.y;
    const int s0 = blockIdx.x << 5;
    const float* qbase = Q + ((size_t)bh * S_LEN + s0) * 64;
    for (int i = threadIdx.x; i < 32 * 64; i += 320)
        Qs[i >> 6][i & 63] = qbase[i];
    __syncthreads();

    const int r = threadIdx.x;
    if (r < NREL) {
        float4 e[16];
        #pragma unroll
        for (int j = 0; j < 16; ++j)
            e[j] = *reinterpret_cast<const float4*>(&rel[(size_t)r * 64 + 4 * j]);
        ushort_t* orow = qrel + ((size_t)bh * S_LEN + s0) * NREL + r;
        for (int s = 0; s < 32; ++s) {
            float acc = 0.f;
            #pragma unroll
            for (int j = 0; j < 16; ++j) {
                float4 q4 = *reinterpret_cast<const float4*>(&Qs[s][4 * j]);
                acc += q4.x*e[j].x + q4.y*e[j].y + q4.z*e[j].z + q4.w*e[j].w;
            }
            orow[(size_t)s * NREL] = f2bf(acc);
        }
    }
}

// ---------------------------------------------------------------------------
// MFMA flash attention. Block = 64 q-rows x one bh, 4 waves (16 q each).
// K (hi/lo) and V^T staged via global_load_lds from pre-tiled global buffers.
// QK^T: 3-pass split MFMA. P redistributed via per-wave fp32 LDS [64k][69q].
// PV: single-pass bf16. Output written as hi/lo bf16 in final-GEMM-tiled form.
// ---------------------------------------------------------------------------
__global__ __launch_bounds__(256, 2)
void attn_kernel(const float* __restrict__ Q, const ushort_t* __restrict__ Kth,
                 const ushort_t* __restrict__ Ktl, const ushort_t* __restrict__ Vth,
                 const ushort_t* __restrict__ QR,
                 ushort_t* __restrict__ AOh, ushort_t* __restrict__ AOl)
{
    __shared__ __align__(16) char lds[24576 + 64 * 69 * 4];
    float* P = (float*)(lds + 24576);            // [k 64][q 69]

    const int bh = blockIdx.y;
    const int q0 = blockIdx.x << 6;
    const int tid = threadIdx.x;
    const int w = tid >> 6;
    const int l = tid & 63;
    const int r16 = l & 15, kq = l >> 4;

    // --- Q fragments (A-operand row = q0 + w*16 + r16), hi/lo
    const int q_l = q0 + w * 16 + r16;
    bf16x8 qh[2], ql[2];
    {
        const float* qrow = Q + (((size_t)bh << 10) + q_l) * 64;
        #pragma unroll
        for (int c = 0; c < 2; ++c) {
            float4 a = *reinterpret_cast<const float4*>(qrow + c * 32 + kq * 8);
            float4 b = *reinterpret_cast<const float4*>(qrow + c * 32 + kq * 8 + 4);
            float v[8] = {a.x, a.y, a.z, a.w, b.x, b.y, b.z, b.w};
            #pragma unroll
            for (int i = 0; i < 8; ++i) {
                ushort_t h = f2bf(v[i]);
                qh[c][i] = (short)h;
                ql[c][i] = (short)f2bf(v[i] - bf2f(h));
            }
        }
    }

    // --- stats rows: q = qs_base + r (r=0..3)
    const int qs_base = q0 + w * 16 + kq * 4;
    float qr_lo[4], qr_hi[4];
    #pragma unroll
    for (int r = 0; r < 4; ++r) {
        const ushort_t* p = QR + ((size_t)((bh << 10) + qs_base + r)) * NREL;
        qr_lo[r] = bf2f(p[0]);
        qr_hi[r] = bf2f(p[256]);
    }

    float m_run[4] = {-1e30f, -1e30f, -1e30f, -1e30f};
    float l_run[4] = {0.f, 0.f, 0.f, 0.f};
    f32x4 accO[4] = {};

    const int wb = (tid & 192) << 4;   // wave-uniform LDS byte base for staging

    for (int kt = 0; kt < S_LEN; kt += 64) {
        __syncthreads();   // buffer free (all waves done with prev tile reads)

        // ---- stage Kh | Kl | Vt (8 KB each), linear chunks
        {
            const size_t tbase = ((size_t)(bh * 16) + (kt >> 6)) * 8192;
            const char* gK = (const char*)Kth + tbase;
            const char* gL = (const char*)Ktl + tbase;
            const char* gV = (const char*)Vth + tbase;
            #pragma unroll
            for (int i = 0; i < 2; ++i) {
                load_lds_16(gK + i * 4096 + tid * 16, lds + i * 4096 + wb);
                load_lds_16(gL + i * 4096 + tid * 16, lds + 8192 + i * 4096 + wb);
                load_lds_16(gV + i * 4096 + tid * 16, lds + 16384 + i * 4096 + wb);
            }
        }

        // ---- rel-position bias (issue loads before the staging barrier)
        float bias[4][4];   // [n][r]
        if (kt - q0 >= 192) {
            #pragma unroll
            for (int n = 0; n < 4; ++n)
                #pragma unroll
                for (int r = 0; r < 4; ++r) bias[n][r] = qr_hi[r];
        } else if (q0 - kt >= 192) {
            #pragma unroll
            for (int n = 0; n < 4; ++n)
                #pragma unroll
                for (int r = 0; r < 4; ++r) bias[n][r] = qr_lo[r];
        } else {
            const int base_d = kt - q0 - w * 16 - kq * 4 + 128 + r16;
            #pragma unroll
            for (int r = 0; r < 4; ++r) {
                const ushort_t* qrp = QR + ((size_t)((bh << 10) + qs_base + r)) * NREL;
                #pragma unroll
                for (int n = 0; n < 4; ++n) {
                    int dlt = base_d + n * 16 - r;
                    dlt = dlt < 0 ? 0 : (dlt > 256 ? 256 : dlt);
                    bias[n][r] = bf2f(qrp[dlt]);
                }
            }
        }

        __syncthreads();   // staging complete (vmcnt drained)

        // ---- QK^T (3-pass split)
        f32x4 S[4] = {};
        const bf16x8* cK = reinterpret_cast<const bf16x8*>(lds);
        const bf16x8* cL = reinterpret_cast<const bf16x8*>(lds + 8192);
        #pragma unroll
        for (int c = 0; c < 2; ++c) {
            bf16x8 kh[4], kl[4];
            #pragma unroll
            for (int n = 0; n < 4; ++n) {
                const int idx = (c * 4 + kq) * 64 + n * 16 + r16;
                kh[n] = cK[idx]; kl[n] = cL[idx];
            }
            #pragma unroll
            for (int n = 0; n < 4; ++n) {
                S[n] = __builtin_amdgcn_mfma_f32_16x16x32_bf16(qh[c], kh[n], S[n], 0, 0, 0);
                S[n] = __builtin_amdgcn_mfma_f32_16x16x32_bf16(qh[c], kl[n], S[n], 0, 0, 0);
                S[n] = __builtin_amdgcn_mfma_f32_16x16x32_bf16(ql[c], kh[n], S[n], 0, 0, 0);
            }
        }

        // ---- softmax (stats per lane for 4 q-rows; reduce over 16 lanes)
        float pv[4][4];
        float tmax[4] = {-1e30f, -1e30f, -1e30f, -1e30f};
        #pragma unroll
        for (int n = 0; n < 4; ++n)
            #pragma unroll
            for (int r = 0; r < 4; ++r) {
                const float s = S[n][r] + bias[n][r];
                pv[n][r] = s;
                tmax[r] = fmaxf(tmax[r], s);
            }
        #pragma unroll
        for (int r = 0; r < 4; ++r) {
            tmax[r] = fmaxf(tmax[r], __shfl_xor(tmax[r], 1));
            tmax[r] = fmaxf(tmax[r], __shfl_xor(tmax[r], 2));
            tmax[r] = fmaxf(tmax[r], __shfl_xor(tmax[r], 4));
            tmax[r] = fmaxf(tmax[r], __shfl_xor(tmax[r], 8));
        }
        float corr[4], psum[4] = {0.f, 0.f, 0.f, 0.f};
        #pragma unroll
        for (int r = 0; r < 4; ++r) {
            const float m_new = fmaxf(m_run[r], tmax[r]);
            corr[r] = __expf(m_run[r] - m_new);
            m_run[r] = m_new;
        }
        #pragma unroll
        for (int n = 0; n < 4; ++n)
            #pragma unroll
            for (int r = 0; r < 4; ++r) {
                pv[n][r] = __expf(pv[n][r] - m_run[r]);
                psum[r] += pv[n][r];
            }
        #pragma unroll
        for (int r = 0; r < 4; ++r) {
            psum[r] += __shfl_xor(psum[r], 1);
            psum[r] += __shfl_xor(psum[r], 2);
            psum[r] += __shfl_xor(psum[r], 4);
            psum[r] += __shfl_xor(psum[r], 8);
            l_run[r] = l_run[r] * corr[r] + psum[r];
        }
        #pragma unroll
        for (int n = 0; n < 4; ++n)
            #pragma unroll
            for (int r = 0; r < 4; ++r) accO[n][r] *= corr[r];

        // ---- P -> LDS (fp32, [k][69])
        #pragma unroll
        for (int n = 0; n < 4; ++n)
            #pragma unroll
            for (int r = 0; r < 4; ++r)
                P[(n * 16 + r16) * 69 + (w * 16 + kq * 4 + r)] = pv[n][r];

        __syncthreads();   // cross-lane P visibility

        // ---- PV (A = P rows, B = V^T rows)
        const bf16x8* cV = reinterpret_cast<const bf16x8*>(lds + 16384);
        #pragma unroll
        for (int c = 0; c < 2; ++c) {
            bf16x8 pa;
            #pragma unroll
            for (int j = 0; j < 8; ++j)
                pa[j] = (short)f2bf(P[(c * 32 + kq * 8 + j) * 69 + (w * 16 + r16)]);
            #pragma unroll
            for (int n = 0; n < 4; ++n) {
                const bf16x8 vf = cV[(c * 4 + kq) * 64 + n * 16 + r16];
                accO[n] = __builtin_amdgcn_mfma_f32_16x16x32_bf16(pa, vf, accO[n], 0, 0, 0);
            }
        }
    }

    // ---- epilogue: normalize, split hi/lo, write final-GEMM tiled layout
    float inv[4];
    #pragma unroll
    for (int r = 0; r < 4; ++r) inv[r] = 1.f / l_run[r];
    #pragma unroll
    for (int n = 0; n < 4; ++n)
        #pragma unroll
        for (int r = 0; r < 4; ++r) {
            const float v = accO[n][r] * inv[r];
            const ushort_t h = f2bf(v);
            const ushort_t lo = f2bf(v - bf2f(h));
            const int r_g  = ((bh >> 4) << 10) + qs_base + r;
            const int kcol = ((bh & 15) << 6) + n * 16 + r16;
            const size_t idx = ((((size_t)(r_g >> 7) * 32 + (kcol >> 5)) * 4
                                + ((kcol >> 3) & 3)) * 128 + (r_g & 127)) * 8 + (kcol & 7);
            AOh[idx] = h;
            AOl[idx] = lo;
        }
}

// ---------------------------------------------------------------------------
extern "C" void kernel_launch(void* const* d_in, const int* in_sizes, int n_in,
                              void* d_out, int out_size, void* d_ws, size_t ws_size,
                              hipStream_t stream)
{
    const float* x   = (const float*)d_in[0];
    const float* Wq  = (const float*)d_in[1];
    const float* bq  = (const float*)d_in[2];
    const float* Wk  = (const float*)d_in[3];
    const float* bk  = (const float*)d_in[4];
    const float* Wv  = (const float*)d_in[5];
    const float* bv  = (const float*)d_in[6];
    const float* Wo  = (const float*)d_in[7];
    const float* bo  = (const float*)d_in[8];
    const float* rel = (const float*)d_in[9];
    float* out = (float*)d_out;

    char* W = (char*)d_ws;
    float*    Qb  = (float*)   (W);                 // 16 MB fp32 Q (attn + qrel)
    ushort_t* QR  = (ushort_t*)(W + 16777216);      // 33.7 MB bf16 Qrel
    ushort_t* Kth = (ushort_t*)(W + 50462720);      // 8 MB
    ushort_t* Ktl = (ushort_t*)(W + 58851328);      // 8 MB
    ushort_t* Vth = (ushort_t*)(W + 67239936);      // 8 MB
    ushort_t* xh  = (ushort_t*)(W + 75628544);      // 8 MB
    ushort_t* xl  = (ushort_t*)(W + 84017152);      // 8 MB
    ushort_t* wqh = (ushort_t*)(W + 92405760);      // 2 MB each
    ushort_t* wkh = (ushort_t*)(W + 94502912);
    ushort_t* wvh = (ushort_t*)(W + 96600064);
    ushort_t* woh = (ushort_t*)(W + 98697216);
    ushort_t* wql = (ushort_t*)(W + 100794368);
    ushort_t* wkl = (ushort_t*)(W + 102891520);
    ushort_t* wvl = (ushort_t*)(W + 104988672);
    ushort_t* wol = (ushort_t*)(W + 107085824);
    ushort_t* AOh = (ushort_t*)(W + 109182976);     // 8 MB
    ushort_t* AOl = (ushort_t*)(W + 117571584);     // 8 MB  (end 125,960,192)

    convert_split<<<2048, 256, 0, stream>>>(x,  xh,  xl);
    convert_split<<<512,  256, 0, stream>>>(Wq, wqh, wql);
    convert_split<<<512,  256, 0, stream>>>(Wk, wkh, wkl);
    convert_split<<<512,  256, 0, stream>>>(Wv, wvh, wvl);
    convert_split<<<512,  256, 0, stream>>>(Wo, woh, wol);

    dim3 gg(8, 32), gb(256);
    gemm_split<1><<<gg, gb, 0, stream>>>(xh, xl, wqh, wql, bq, Qb, nullptr, nullptr, 0.125f);
    gemm_split<2><<<gg, gb, 0, stream>>>(xh, xl, wkh, wkl, bk, nullptr, Kth, Ktl, 1.0f);
    gemm_split<3><<<gg, gb, 0, stream>>>(xh, xl, wvh, wvl, bv, nullptr, Vth, nullptr, 1.0f);

    qrel_kernel<<<dim3(32, 64), dim3(320), 0, stream>>>(Qb, rel, QR);

    attn_kernel<<<dim3(16, 64), dim3(256), 0, stream>>>(Qb, Kth, Ktl, Vth, QR, AOh, AOl);

    gemm_split<0><<<gg, gb, 0, stream>>>(AOh, AOl, woh, wol, bo, out, nullptr, nullptr, 1.0f);
}

// Round 5
// 334.164 us; speedup vs baseline: 3.4222x; 1.3956x over previous
//
#include <hip/hip_runtime.h>
#include <math.h>

#define S_LEN 1024
#define NREL  257
#define QRST  272          // QR row stride (padded)

typedef unsigned short ushort_t;
typedef __attribute__((ext_vector_type(8))) short bf16x8;
typedef __attribute__((ext_vector_type(4))) float f32x4;

__device__ inline ushort_t f2bf(float f) {
    unsigned u = __float_as_uint(f);
    unsigned r = u + 0x7FFFu + ((u >> 16) & 1u);   // RNE
    return (ushort_t)(r >> 16);
}
__device__ inline float bf2f(ushort_t h) {
    return __uint_as_float(((unsigned)h) << 16);
}

__device__ inline void load_lds_16(const void* g, void* l) {
    __builtin_amdgcn_global_load_lds(
        (const __attribute__((address_space(1))) void*)g,
        (__attribute__((address_space(3))) void*)l, 16, 0, 0);
}

// ---------------------------------------------------------------------------
// Split fp32 [R][1024] into hi/lo bf16 GEMM-operand tiles:
//   chunk t: t = ((mtile*32 + ktile)*4 + kc)*128 + row128
// ---------------------------------------------------------------------------
__global__ __launch_bounds__(256)
void convert_split(const float* __restrict__ src, ushort_t* __restrict__ hi,
                   ushort_t* __restrict__ lo)
{
    const int t = blockIdx.x * 256 + threadIdx.x;
    const int row128 = t & 127;
    const int kc     = (t >> 7) & 3;
    const int ktile  = (t >> 9) & 31;
    const int mtile  = t >> 14;
    const float* s = src + ((size_t)(mtile * 128 + row128) * 1024) + ktile * 32 + kc * 8;
    float4 v0 = *reinterpret_cast<const float4*>(s);
    float4 v1 = *reinterpret_cast<const float4*>(s + 4);
    float v[8] = {v0.x, v0.y, v0.z, v0.w, v1.x, v1.y, v1.z, v1.w};
    union { ushort_t u[8]; int4 q; } H, L;
    #pragma unroll
    for (int i = 0; i < 8; ++i) {
        ushort_t h = f2bf(v[i]);
        H.u[i] = h;
        L.u[i] = f2bf(v[i] - bf2f(h));
    }
    reinterpret_cast<int4*>(hi)[t] = H.q;
    reinterpret_cast<int4*>(lo)[t] = L.q;
}

// ---------------------------------------------------------------------------
// rel_emb fp32 [257][64] -> bf16 chunk layout [8][272] chunks (zero-padded):
//   chunk t = ck*272 + row holds rel[row][ck*8 .. ck*8+7]; 2304 chunks total.
// ---------------------------------------------------------------------------
__global__ __launch_bounds__(256)
void rel_convert(const float* __restrict__ rel, ushort_t* __restrict__ relc)
{
    const int t = blockIdx.x * 256 + threadIdx.x;   // 0..2303
    const int ck = t / 272, row = t % 272;
    union { ushort_t u[8]; int4 q; } H;
    #pragma unroll
    for (int i = 0; i < 8; ++i) H.u[i] = 0;
    if (ck < 8 && row < NREL) {
        const float* s = rel + (size_t)row * 64 + ck * 8;
        float4 v0 = *reinterpret_cast<const float4*>(s);
        float4 v1 = *reinterpret_cast<const float4*>(s + 4);
        float v[8] = {v0.x, v0.y, v0.z, v0.w, v1.x, v1.y, v1.z, v1.w};
        #pragma unroll
        for (int i = 0; i < 8; ++i) H.u[i] = f2bf(v[i]);
    }
    reinterpret_cast<int4*>(relc)[t] = H.q;
}

// ---------------------------------------------------------------------------
// Split-bf16 MFMA GEMM. 128x128 tile, BK=32, 4 waves, 3 MFMA passes (hh,hl,lh)
// Epilogue MODE:
//  0: fp32 out[r*1024 + c]
//  2: K attn-tiled hi/lo bf16
//  3: V^T attn-tiled hi bf16
//  4: Q row-major hi/lo bf16: idx = ((b*16+nh)*1024+s)*64 + d
// ---------------------------------------------------------------------------
template<int MODE>
__global__ __launch_bounds__(256)
void gemm_split(const ushort_t* __restrict__ Ah, const ushort_t* __restrict__ Al,
                const ushort_t* __restrict__ Bh, const ushort_t* __restrict__ Bl,
                const float* __restrict__ bias, float* __restrict__ out,
                ushort_t* __restrict__ ohi, ushort_t* __restrict__ olo, float scale)
{
    __shared__ __align__(16) short sm[2][4][4096];
    const int tid  = threadIdx.x;
    const int wave = tid >> 6, lane = tid & 63;
    const int wm = wave >> 1, wn = wave & 1;
    const int r16 = lane & 15, kq = lane >> 4;
    const int mtile = blockIdx.y;
    const int ntile = blockIdx.x;
    const int wb = (tid & ~63) << 3;

    f32x4 acc[4][4] = {};

    auto stage = [&](int buf, int kt) {
        const ushort_t* g[4] = {
            Ah + ((size_t)(mtile * 32 + kt) << 12),
            Al + ((size_t)(mtile * 32 + kt) << 12),
            Bh + ((size_t)(ntile * 32 + kt) << 12),
            Bl + ((size_t)(ntile * 32 + kt) << 12)};
        #pragma unroll
        for (int t4 = 0; t4 < 4; ++t4) {
            load_lds_16(g[t4] + ((size_t)tid << 3),         &sm[buf][t4][wb]);
            load_lds_16(g[t4] + ((size_t)(tid + 256) << 3), &sm[buf][t4][wb + 2048]);
        }
    };

    stage(0, 0);
    __syncthreads();

    for (int kt = 0; kt < 32; ++kt) {
        const int cur = kt & 1;
        if (kt + 1 < 32) stage(cur ^ 1, kt + 1);

        const bf16x8* pAh = reinterpret_cast<const bf16x8*>(sm[cur][0]);
        const bf16x8* pAl = reinterpret_cast<const bf16x8*>(sm[cur][1]);
        const bf16x8* pBh = reinterpret_cast<const bf16x8*>(sm[cur][2]);
        const bf16x8* pBl = reinterpret_cast<const bf16x8*>(sm[cur][3]);

        bf16x8 afh[4], afl[4], bfh[4], bfl[4];
        #pragma unroll
        for (int m = 0; m < 4; ++m) {
            const int ch = kq * 128 + wm * 64 + m * 16 + r16;
            afh[m] = pAh[ch]; afl[m] = pAl[ch];
        }
        #pragma unroll
        for (int n = 0; n < 4; ++n) {
            const int ch = kq * 128 + wn * 64 + n * 16 + r16;
            bfh[n] = pBh[ch]; bfl[n] = pBl[ch];
        }
        #pragma unroll
        for (int m = 0; m < 4; ++m)
            #pragma unroll
            for (int n = 0; n < 4; ++n) {
                acc[m][n] = __builtin_amdgcn_mfma_f32_16x16x32_bf16(afh[m], bfh[n], acc[m][n], 0, 0, 0);
                acc[m][n] = __builtin_amdgcn_mfma_f32_16x16x32_bf16(afh[m], bfl[n], acc[m][n], 0, 0, 0);
                acc[m][n] = __builtin_amdgcn_mfma_f32_16x16x32_bf16(afl[m], bfh[n], acc[m][n], 0, 0, 0);
            }
        __syncthreads();
    }

    const int row0 = (mtile << 7) + wm * 64;
    const int col0 = (ntile << 7) + wn * 64;
    #pragma unroll
    for (int n = 0; n < 4; ++n) {
        const int col = col0 + n * 16 + r16;
        const float bc = bias[col];
        #pragma unroll
        for (int m = 0; m < 4; ++m) {
            #pragma unroll
            for (int r = 0; r < 4; ++r) {
                const int row = row0 + m * 16 + kq * 4 + r;
                const float val = (acc[m][n][r] + bc) * scale;
                if (MODE == 0) {
                    out[(size_t)row * 1024 + col] = val;
                } else if (MODE == 2) {
                    const int b = row >> 10, s = row & 1023;
                    const int nh = col >> 6, d = col & 63;
                    const size_t cidx = (((size_t)(b * 16 + nh) << 13) + ((s >> 6) << 9)
                                        + ((d >> 3) << 6) + (s & 63)) * 8 + (d & 7);
                    const ushort_t h = f2bf(val);
                    ohi[cidx] = h;
                    olo[cidx] = f2bf(val - bf2f(h));
                } else if (MODE == 3) {  // V^T
                    const int b = row >> 10, s = row & 1023;
                    const int nh = col >> 6, d = col & 63;
                    const int kk = s & 63;
                    const size_t cidx = (((size_t)(b * 16 + nh) << 13) + ((s >> 6) << 9)
                                        + ((kk >> 3) << 6) + d) * 8 + (kk & 7);
                    ohi[cidx] = f2bf(val);
                } else {  // MODE 4: Q row-major hi/lo
                    const int b = row >> 10, s = row & 1023;
                    const int nh = col >> 6, d = col & 63;
                    const size_t idx = ((((size_t)(b * 16 + nh)) << 10 | (size_t)s) << 6) + d;
                    const ushort_t h = f2bf(val);
                    ohi[idx] = h;
                    olo[idx] = f2bf(val - bf2f(h));
                }
            }
        }
    }
}

// ---------------------------------------------------------------------------
// Qrel = Q_hi[65536x64] @ rel^T  -> bf16 QR[65536][272]
// Block: 64 q-rows, 4 waves x 17 n-frags, K=64 (2 MFMA/frag).
// rel staged once per block (2304 chunks, linear global_load_lds).
// ---------------------------------------------------------------------------
__global__ __launch_bounds__(256)
void qrel_gemm(const ushort_t* __restrict__ Qh, const ushort_t* __restrict__ relc,
               ushort_t* __restrict__ QR)
{
    __shared__ __align__(16) char lds[36864];
    const int tid = threadIdx.x;
    const int w = tid >> 6, l = tid & 63;
    const int r16 = l & 15, kq = l >> 4;
    const int blk = blockIdx.x;
    const int wb = (tid & 192) << 4;   // wave-uniform LDS base

    #pragma unroll
    for (int i = 0; i < 9; ++i)
        load_lds_16((const char*)relc + i * 4096 + tid * 16, lds + i * 4096 + wb);

    // A fragments while staging is in flight
    const int qrow = (blk << 6) + w * 16 + r16;
    bf16x8 ah[2];
    ah[0] = *reinterpret_cast<const bf16x8*>(Qh + (size_t)qrow * 64 + kq * 8);
    ah[1] = *reinterpret_cast<const bf16x8*>(Qh + (size_t)qrow * 64 + 32 + kq * 8);

    __syncthreads();   // staging complete

    f32x4 S[17] = {};
    const bf16x8* cB = reinterpret_cast<const bf16x8*>(lds);
    #pragma unroll
    for (int c = 0; c < 2; ++c) {
        #pragma unroll
        for (int n = 0; n < 17; ++n) {
            const bf16x8 bf = cB[(c * 4 + kq) * 272 + n * 16 + r16];
            S[n] = __builtin_amdgcn_mfma_f32_16x16x32_bf16(ah[c], bf, S[n], 0, 0, 0);
        }
    }

    const int qbase = (blk << 6) + w * 16 + kq * 4;
    #pragma unroll
    for (int n = 0; n < 17; ++n) {
        const int col = n * 16 + r16;
        #pragma unroll
        for (int r = 0; r < 4; ++r)
            QR[(size_t)(qbase + r) * QRST + col] = f2bf(S[n][r]);
    }
}

// ---------------------------------------------------------------------------
// MFMA flash attention. Block = 64 q-rows x one bh, 4 waves.
// Q hi/lo read as bf16x8 from row-major bf16 Q. QR stride 272.
// ---------------------------------------------------------------------------
__global__ __launch_bounds__(256, 2)
void attn_kernel(const ushort_t* __restrict__ Qhg, const ushort_t* __restrict__ Qlg,
                 const ushort_t* __restrict__ Kth, const ushort_t* __restrict__ Ktl,
                 const ushort_t* __restrict__ Vth, const ushort_t* __restrict__ QR,
                 ushort_t* __restrict__ AOh, ushort_t* __restrict__ AOl)
{
    __shared__ __align__(16) char lds[24576 + 64 * 69 * 4];
    float* P = (float*)(lds + 24576);            // [k 64][q 69]

    const int bh = blockIdx.y;
    const int q0 = blockIdx.x << 6;
    const int tid = threadIdx.x;
    const int w = tid >> 6;
    const int l = tid & 63;
    const int r16 = l & 15, kq = l >> 4;

    // --- Q fragments (A-operand row = q0 + w*16 + r16), hi/lo
    const int q_l = q0 + w * 16 + r16;
    bf16x8 qh[2], ql[2];
    {
        const size_t qoff = (((size_t)bh << 10) + q_l) * 64;
        #pragma unroll
        for (int c = 0; c < 2; ++c) {
            qh[c] = *reinterpret_cast<const bf16x8*>(Qhg + qoff + c * 32 + kq * 8);
            ql[c] = *reinterpret_cast<const bf16x8*>(Qlg + qoff + c * 32 + kq * 8);
        }
    }

    // --- stats rows: q = qs_base + r (r=0..3)
    const int qs_base = q0 + w * 16 + kq * 4;
    float qr_lo[4], qr_hi[4];
    #pragma unroll
    for (int r = 0; r < 4; ++r) {
        const ushort_t* p = QR + ((size_t)((bh << 10) + qs_base + r)) * QRST;
        qr_lo[r] = bf2f(p[0]);
        qr_hi[r] = bf2f(p[256]);
    }

    float m_run[4] = {-1e30f, -1e30f, -1e30f, -1e30f};
    float l_run[4] = {0.f, 0.f, 0.f, 0.f};
    f32x4 accO[4] = {};

    const int wb = (tid & 192) << 4;

    for (int kt = 0; kt < S_LEN; kt += 64) {
        __syncthreads();

        // ---- stage Kh | Kl | Vt (8 KB each), linear chunks
        {
            const size_t tbase = ((size_t)(bh * 16) + (kt >> 6)) * 8192;
            const char* gK = (const char*)Kth + tbase;
            const char* gL = (const char*)Ktl + tbase;
            const char* gV = (const char*)Vth + tbase;
            #pragma unroll
            for (int i = 0; i < 2; ++i) {
                load_lds_16(gK + i * 4096 + tid * 16, lds + i * 4096 + wb);
                load_lds_16(gL + i * 4096 + tid * 16, lds + 8192 + i * 4096 + wb);
                load_lds_16(gV + i * 4096 + tid * 16, lds + 16384 + i * 4096 + wb);
            }
        }

        // ---- rel-position bias
        float bias[4][4];   // [n][r]
        if (kt - q0 >= 192) {
            #pragma unroll
            for (int n = 0; n < 4; ++n)
                #pragma unroll
                for (int r = 0; r < 4; ++r) bias[n][r] = qr_hi[r];
        } else if (q0 - kt >= 192) {
            #pragma unroll
            for (int n = 0; n < 4; ++n)
                #pragma unroll
                for (int r = 0; r < 4; ++r) bias[n][r] = qr_lo[r];
        } else {
            const int base_d = kt - q0 - w * 16 - kq * 4 + 128 + r16;
            #pragma unroll
            for (int r = 0; r < 4; ++r) {
                const ushort_t* qrp = QR + ((size_t)((bh << 10) + qs_base + r)) * QRST;
                #pragma unroll
                for (int n = 0; n < 4; ++n) {
                    int dlt = base_d + n * 16 - r;
                    dlt = dlt < 0 ? 0 : (dlt > 256 ? 256 : dlt);
                    bias[n][r] = bf2f(qrp[dlt]);
                }
            }
        }

        __syncthreads();   // staging complete

        // ---- QK^T (3-pass split)
        f32x4 S[4] = {};
        const bf16x8* cK = reinterpret_cast<const bf16x8*>(lds);
        const bf16x8* cL = reinterpret_cast<const bf16x8*>(lds + 8192);
        #pragma unroll
        for (int c = 0; c < 2; ++c) {
            bf16x8 kh[4], kl[4];
            #pragma unroll
            for (int n = 0; n < 4; ++n) {
                const int idx = (c * 4 + kq) * 64 + n * 16 + r16;
                kh[n] = cK[idx]; kl[n] = cL[idx];
            }
            #pragma unroll
            for (int n = 0; n < 4; ++n) {
                S[n] = __builtin_amdgcn_mfma_f32_16x16x32_bf16(qh[c], kh[n], S[n], 0, 0, 0);
                S[n] = __builtin_amdgcn_mfma_f32_16x16x32_bf16(qh[c], kl[n], S[n], 0, 0, 0);
                S[n] = __builtin_amdgcn_mfma_f32_16x16x32_bf16(ql[c], kh[n], S[n], 0, 0, 0);
            }
        }

        // ---- softmax
        float pv[4][4];
        float tmax[4] = {-1e30f, -1e30f, -1e30f, -1e30f};
        #pragma unroll
        for (int n = 0; n < 4; ++n)
            #pragma unroll
            for (int r = 0; r < 4; ++r) {
                const float s = S[n][r] + bias[n][r];
                pv[n][r] = s;
                tmax[r] = fmaxf(tmax[r], s);
            }
        #pragma unroll
        for (int r = 0; r < 4; ++r) {
            tmax[r] = fmaxf(tmax[r], __shfl_xor(tmax[r], 1));
            tmax[r] = fmaxf(tmax[r], __shfl_xor(tmax[r], 2));
            tmax[r] = fmaxf(tmax[r], __shfl_xor(tmax[r], 4));
            tmax[r] = fmaxf(tmax[r], __shfl_xor(tmax[r], 8));
        }
        float corr[4], psum[4] = {0.f, 0.f, 0.f, 0.f};
        #pragma unroll
        for (int r = 0; r < 4; ++r) {
            const float m_new = fmaxf(m_run[r], tmax[r]);
            corr[r] = __expf(m_run[r] - m_new);
            m_run[r] = m_new;
        }
        #pragma unroll
        for (int n = 0; n < 4; ++n)
            #pragma unroll
            for (int r = 0; r < 4; ++r) {
                pv[n][r] = __expf(pv[n][r] - m_run[r]);
                psum[r] += pv[n][r];
            }
        #pragma unroll
        for (int r = 0; r < 4; ++r) {
            psum[r] += __shfl_xor(psum[r], 1);
            psum[r] += __shfl_xor(psum[r], 2);
            psum[r] += __shfl_xor(psum[r], 4);
            psum[r] += __shfl_xor(psum[r], 8);
            l_run[r] = l_run[r] * corr[r] + psum[r];
        }
        #pragma unroll
        for (int n = 0; n < 4; ++n)
            #pragma unroll
            for (int r = 0; r < 4; ++r) accO[n][r] *= corr[r];

        // ---- P -> LDS (fp32, [k][69])
        #pragma unroll
        for (int n = 0; n < 4; ++n)
            #pragma unroll
            for (int r = 0; r < 4; ++r)
                P[(n * 16 + r16) * 69 + (w * 16 + kq * 4 + r)] = pv[n][r];

        __syncthreads();

        // ---- PV
        const bf16x8* cV = reinterpret_cast<const bf16x8*>(lds + 16384);
        #pragma unroll
        for (int c = 0; c < 2; ++c) {
            bf16x8 pa;
            #pragma unroll
            for (int j = 0; j < 8; ++j)
                pa[j] = (short)f2bf(P[(c * 32 + kq * 8 + j) * 69 + (w * 16 + r16)]);
            #pragma unroll
            for (int n = 0; n < 4; ++n) {
                const bf16x8 vf = cV[(c * 4 + kq) * 64 + n * 16 + r16];
                accO[n] = __builtin_amdgcn_mfma_f32_16x16x32_bf16(pa, vf, accO[n], 0, 0, 0);
            }
        }
    }

    // ---- epilogue
    float inv[4];
    #pragma unroll
    for (int r = 0; r < 4; ++r) inv[r] = 1.f / l_run[r];
    #pragma unroll
    for (int n = 0; n < 4; ++n)
        #pragma unroll
        for (int r = 0; r < 4; ++r) {
            const float v = accO[n][r] * inv[r];
            const ushort_t h = f2bf(v);
            const ushort_t lo = f2bf(v - bf2f(h));
            const int r_g  = ((bh >> 4) << 10) + qs_base + r;
            const int kcol = ((bh & 15) << 6) + n * 16 + r16;
            const size_t idx = ((((size_t)(r_g >> 7) * 32 + (kcol >> 5)) * 4
                                + ((kcol >> 3) & 3)) * 128 + (r_g & 127)) * 8 + (kcol & 7);
            AOh[idx] = h;
            AOl[idx] = lo;
        }
}

// ---------------------------------------------------------------------------
extern "C" void kernel_launch(void* const* d_in, const int* in_sizes, int n_in,
                              void* d_out, int out_size, void* d_ws, size_t ws_size,
                              hipStream_t stream)
{
    const float* x   = (const float*)d_in[0];
    const float* Wq  = (const float*)d_in[1];
    const float* bq  = (const float*)d_in[2];
    const float* Wk  = (const float*)d_in[3];
    const float* bk  = (const float*)d_in[4];
    const float* Wv  = (const float*)d_in[5];
    const float* bv  = (const float*)d_in[6];
    const float* Wo  = (const float*)d_in[7];
    const float* bo  = (const float*)d_in[8];
    const float* rel = (const float*)d_in[9];
    float* out = (float*)d_out;

    char* W = (char*)d_ws;
    ushort_t* Qhb = (ushort_t*)(W);                 // 8 MB
    ushort_t* Qlb = (ushort_t*)(W + 8388608);       // 8 MB
    ushort_t* QR  = (ushort_t*)(W + 16777216);      // 35,651,584 B
    ushort_t* Kth = (ushort_t*)(W + 52428800);      // 8 MB
    ushort_t* Ktl = (ushort_t*)(W + 60817408);      // 8 MB
    ushort_t* Vth = (ushort_t*)(W + 69206016);      // 8 MB
    ushort_t* xh  = (ushort_t*)(W + 77594624);      // 8 MB
    ushort_t* xl  = (ushort_t*)(W + 85983232);      // 8 MB
    ushort_t* wqh = (ushort_t*)(W + 94371840);      // 2 MB each
    ushort_t* wkh = (ushort_t*)(W + 96468992);
    ushort_t* wvh = (ushort_t*)(W + 98566144);
    ushort_t* woh = (ushort_t*)(W + 100663296);
    ushort_t* wql = (ushort_t*)(W + 102760448);
    ushort_t* wkl = (ushort_t*)(W + 104857600);
    ushort_t* wvl = (ushort_t*)(W + 106954752);
    ushort_t* wol = (ushort_t*)(W + 109051904);
    ushort_t* AOh = (ushort_t*)(W + 111149056);     // 8 MB
    ushort_t* AOl = (ushort_t*)(W + 119537664);     // 8 MB
    ushort_t* relc= (ushort_t*)(W + 127926272);     // 36,864 B (end 127,963,136)

    convert_split<<<2048, 256, 0, stream>>>(x,  xh,  xl);
    convert_split<<<512,  256, 0, stream>>>(Wq, wqh, wql);
    convert_split<<<512,  256, 0, stream>>>(Wk, wkh, wkl);
    convert_split<<<512,  256, 0, stream>>>(Wv, wvh, wvl);
    convert_split<<<512,  256, 0, stream>>>(Wo, woh, wol);
    rel_convert<<<9, 256, 0, stream>>>(rel, relc);

    dim3 gg(8, 32), gb(256);
    gemm_split<4><<<gg, gb, 0, stream>>>(xh, xl, wqh, wql, bq, nullptr, Qhb, Qlb, 0.125f);
    gemm_split<2><<<gg, gb, 0, stream>>>(xh, xl, wkh, wkl, bk, nullptr, Kth, Ktl, 1.0f);
    gemm_split<3><<<gg, gb, 0, stream>>>(xh, xl, wvh, wvl, bv, nullptr, Vth, nullptr, 1.0f);

    qrel_gemm<<<1024, 256, 0, stream>>>(Qhb, relc, QR);

    attn_kernel<<<dim3(16, 64), dim3(256), 0, stream>>>(Qhb, Qlb, Kth, Ktl, Vth, QR, AOh, AOl);

    gemm_split<0><<<gg, gb, 0, stream>>>(AOh, AOl, woh, wol, bo, out, nullptr, nullptr, 1.0f);
}

// Round 6
// 313.341 us; speedup vs baseline: 3.6497x; 1.0665x over previous
//
#include <hip/hip_runtime.h>
#include <math.h>

#define S_LEN 1024
#define NREL  257
#define QRST  272          // QR row stride (padded)

typedef unsigned short ushort_t;
typedef __attribute__((ext_vector_type(8))) short bf16x8;
typedef __attribute__((ext_vector_type(4))) float f32x4;

__device__ inline ushort_t f2bf(float f) {
    unsigned u = __float_as_uint(f);
    unsigned r = u + 0x7FFFu + ((u >> 16) & 1u);   // RNE
    return (ushort_t)(r >> 16);
}
__device__ inline float bf2f(ushort_t h) {
    return __uint_as_float(((unsigned)h) << 16);
}

__device__ inline void load_lds_16(const void* g, void* l) {
    __builtin_amdgcn_global_load_lds(
        (const __attribute__((address_space(1))) void*)g,
        (__attribute__((address_space(3))) void*)l, 16, 0, 0);
}

// ---------------------------------------------------------------------------
// Split fp32 [R][1024] into hi/lo bf16 GEMM-operand tiles:
//   chunk t: t = ((mtile*32 + ktile)*4 + kc)*128 + row128
// ---------------------------------------------------------------------------
__global__ __launch_bounds__(256)
void convert_split(const float* __restrict__ src, ushort_t* __restrict__ hi,
                   ushort_t* __restrict__ lo)
{
    const int t = blockIdx.x * 256 + threadIdx.x;
    const int row128 = t & 127;
    const int kc     = (t >> 7) & 3;
    const int ktile  = (t >> 9) & 31;
    const int mtile  = t >> 14;
    const float* s = src + ((size_t)(mtile * 128 + row128) * 1024) + ktile * 32 + kc * 8;
    float4 v0 = *reinterpret_cast<const float4*>(s);
    float4 v1 = *reinterpret_cast<const float4*>(s + 4);
    float v[8] = {v0.x, v0.y, v0.z, v0.w, v1.x, v1.y, v1.z, v1.w};
    union { ushort_t u[8]; int4 q; } H, L;
    #pragma unroll
    for (int i = 0; i < 8; ++i) {
        ushort_t h = f2bf(v[i]);
        H.u[i] = h;
        L.u[i] = f2bf(v[i] - bf2f(h));
    }
    reinterpret_cast<int4*>(hi)[t] = H.q;
    reinterpret_cast<int4*>(lo)[t] = L.q;
}

// ---------------------------------------------------------------------------
// rel_emb fp32 [257][64] -> bf16 chunk layout [8][272] chunks (zero-padded)
// ---------------------------------------------------------------------------
__global__ __launch_bounds__(256)
void rel_convert(const float* __restrict__ rel, ushort_t* __restrict__ relc)
{
    const int t = blockIdx.x * 256 + threadIdx.x;   // 0..2303
    const int ck = t / 272, row = t % 272;
    union { ushort_t u[8]; int4 q; } H;
    #pragma unroll
    for (int i = 0; i < 8; ++i) H.u[i] = 0;
    if (ck < 8 && row < NREL) {
        const float* s = rel + (size_t)row * 64 + ck * 8;
        float4 v0 = *reinterpret_cast<const float4*>(s);
        float4 v1 = *reinterpret_cast<const float4*>(s + 4);
        float v[8] = {v0.x, v0.y, v0.z, v0.w, v1.x, v1.y, v1.z, v1.w};
        #pragma unroll
        for (int i = 0; i < 8; ++i) H.u[i] = f2bf(v[i]);
    }
    reinterpret_cast<int4*>(relc)[t] = H.q;
}

// ---------------------------------------------------------------------------
// Merged Q/K/V projection GEMM. A = x (hi/lo tiles), B = [Wq;Wk;Wv] tiles
// (ntile 0..7 = Wq, 8..15 = Wk, 16..23 = Wv). 128x128 tile, BK=32, 4 waves,
// 3-pass split MFMA. Epilogue per nsel: Q row-major hi/lo (scaled 0.125),
// K attn-tiled hi/lo, V^T attn-tiled hi.
// ---------------------------------------------------------------------------
__global__ __launch_bounds__(256)
void gemm_qkv(const ushort_t* __restrict__ Ah, const ushort_t* __restrict__ Al,
              const ushort_t* __restrict__ Bh, const ushort_t* __restrict__ Bl,
              const float* __restrict__ bq, const float* __restrict__ bk,
              const float* __restrict__ bv,
              ushort_t* __restrict__ Qhb, ushort_t* __restrict__ Qlb,
              ushort_t* __restrict__ Kth, ushort_t* __restrict__ Ktl,
              ushort_t* __restrict__ Vth)
{
    __shared__ __align__(16) short sm[2][4][4096];
    const int tid  = threadIdx.x;
    const int wave = tid >> 6, lane = tid & 63;
    const int wm = wave >> 1, wn = wave & 1;
    const int r16 = lane & 15, kq = lane >> 4;
    const int mtile = blockIdx.y;
    const int ntile = blockIdx.x;      // 0..23
    const int wb = (tid & ~63) << 3;

    f32x4 acc[4][4] = {};

    auto stage = [&](int buf, int kt) {
        const ushort_t* g[4] = {
            Ah + ((size_t)(mtile * 32 + kt) << 12),
            Al + ((size_t)(mtile * 32 + kt) << 12),
            Bh + ((size_t)(ntile * 32 + kt) << 12),
            Bl + ((size_t)(ntile * 32 + kt) << 12)};
        #pragma unroll
        for (int t4 = 0; t4 < 4; ++t4) {
            load_lds_16(g[t4] + ((size_t)tid << 3),         &sm[buf][t4][wb]);
            load_lds_16(g[t4] + ((size_t)(tid + 256) << 3), &sm[buf][t4][wb + 2048]);
        }
    };

    stage(0, 0);
    __syncthreads();

    for (int kt = 0; kt < 32; ++kt) {
        const int cur = kt & 1;
        if (kt + 1 < 32) stage(cur ^ 1, kt + 1);

        const bf16x8* pAh = reinterpret_cast<const bf16x8*>(sm[cur][0]);
        const bf16x8* pAl = reinterpret_cast<const bf16x8*>(sm[cur][1]);
        const bf16x8* pBh = reinterpret_cast<const bf16x8*>(sm[cur][2]);
        const bf16x8* pBl = reinterpret_cast<const bf16x8*>(sm[cur][3]);

        bf16x8 afh[4], afl[4], bfh[4], bfl[4];
        #pragma unroll
        for (int m = 0; m < 4; ++m) {
            const int ch = kq * 128 + wm * 64 + m * 16 + r16;
            afh[m] = pAh[ch]; afl[m] = pAl[ch];
        }
        #pragma unroll
        for (int n = 0; n < 4; ++n) {
            const int ch = kq * 128 + wn * 64 + n * 16 + r16;
            bfh[n] = pBh[ch]; bfl[n] = pBl[ch];
        }
        #pragma unroll
        for (int m = 0; m < 4; ++m)
            #pragma unroll
            for (int n = 0; n < 4; ++n) {
                acc[m][n] = __builtin_amdgcn_mfma_f32_16x16x32_bf16(afh[m], bfh[n], acc[m][n], 0, 0, 0);
                acc[m][n] = __builtin_amdgcn_mfma_f32_16x16x32_bf16(afh[m], bfl[n], acc[m][n], 0, 0, 0);
                acc[m][n] = __builtin_amdgcn_mfma_f32_16x16x32_bf16(afl[m], bfh[n], acc[m][n], 0, 0, 0);
            }
        __syncthreads();
    }

    const int nsel = ntile >> 3;                       // 0=Q 1=K 2=V (block-uniform)
    const float scale = (nsel == 0) ? 0.125f : 1.0f;
    const float* bp = (nsel == 0) ? bq : ((nsel == 1) ? bk : bv);
    const int row0 = (mtile << 7) + wm * 64;
    const int col0 = ((ntile & 7) << 7) + wn * 64;     // within this output's 1024

    #pragma unroll
    for (int n = 0; n < 4; ++n) {
        const int col = col0 + n * 16 + r16;
        const float bc = bp[col];
        #pragma unroll
        for (int m = 0; m < 4; ++m) {
            #pragma unroll
            for (int r = 0; r < 4; ++r) {
                const int row = row0 + m * 16 + kq * 4 + r;
                const float val = (acc[m][n][r] + bc) * scale;
                const int b = row >> 10, s = row & 1023;
                const int nh = col >> 6, d = col & 63;
                if (nsel == 0) {            // Q row-major hi/lo
                    const size_t idx = ((((size_t)(b * 16 + nh)) << 10 | (size_t)s) << 6) + d;
                    const ushort_t h = f2bf(val);
                    Qhb[idx] = h;
                    Qlb[idx] = f2bf(val - bf2f(h));
                } else if (nsel == 1) {     // K attn-tiled hi/lo
                    const size_t cidx = (((size_t)(b * 16 + nh) << 13) + ((s >> 6) << 9)
                                        + ((d >> 3) << 6) + (s & 63)) * 8 + (d & 7);
                    const ushort_t h = f2bf(val);
                    Kth[cidx] = h;
                    Ktl[cidx] = f2bf(val - bf2f(h));
                } else {                    // V^T attn-tiled hi
                    const int kk = s & 63;
                    const size_t cidx = (((size_t)(b * 16 + nh) << 13) + ((s >> 6) << 9)
                                        + ((kk >> 3) << 6) + d) * 8 + (kk & 7);
                    Vth[cidx] = f2bf(val);
                }
            }
        }
    }
}

// ---------------------------------------------------------------------------
// Final GEMM: out = AO @ Wo^T + bo (fp32 out), split-bf16 3-pass MFMA.
// ---------------------------------------------------------------------------
__global__ __launch_bounds__(256)
void gemm_out(const ushort_t* __restrict__ Ah, const ushort_t* __restrict__ Al,
              const ushort_t* __restrict__ Bh, const ushort_t* __restrict__ Bl,
              const float* __restrict__ bias, float* __restrict__ out)
{
    __shared__ __align__(16) short sm[2][4][4096];
    const int tid  = threadIdx.x;
    const int wave = tid >> 6, lane = tid & 63;
    const int wm = wave >> 1, wn = wave & 1;
    const int r16 = lane & 15, kq = lane >> 4;
    const int mtile = blockIdx.y;
    const int ntile = blockIdx.x;
    const int wb = (tid & ~63) << 3;

    f32x4 acc[4][4] = {};

    auto stage = [&](int buf, int kt) {
        const ushort_t* g[4] = {
            Ah + ((size_t)(mtile * 32 + kt) << 12),
            Al + ((size_t)(mtile * 32 + kt) << 12),
            Bh + ((size_t)(ntile * 32 + kt) << 12),
            Bl + ((size_t)(ntile * 32 + kt) << 12)};
        #pragma unroll
        for (int t4 = 0; t4 < 4; ++t4) {
            load_lds_16(g[t4] + ((size_t)tid << 3),         &sm[buf][t4][wb]);
            load_lds_16(g[t4] + ((size_t)(tid + 256) << 3), &sm[buf][t4][wb + 2048]);
        }
    };

    stage(0, 0);
    __syncthreads();

    for (int kt = 0; kt < 32; ++kt) {
        const int cur = kt & 1;
        if (kt + 1 < 32) stage(cur ^ 1, kt + 1);

        const bf16x8* pAh = reinterpret_cast<const bf16x8*>(sm[cur][0]);
        const bf16x8* pAl = reinterpret_cast<const bf16x8*>(sm[cur][1]);
        const bf16x8* pBh = reinterpret_cast<const bf16x8*>(sm[cur][2]);
        const bf16x8* pBl = reinterpret_cast<const bf16x8*>(sm[cur][3]);

        bf16x8 afh[4], afl[4], bfh[4], bfl[4];
        #pragma unroll
        for (int m = 0; m < 4; ++m) {
            const int ch = kq * 128 + wm * 64 + m * 16 + r16;
            afh[m] = pAh[ch]; afl[m] = pAl[ch];
        }
        #pragma unroll
        for (int n = 0; n < 4; ++n) {
            const int ch = kq * 128 + wn * 64 + n * 16 + r16;
            bfh[n] = pBh[ch]; bfl[n] = pBl[ch];
        }
        #pragma unroll
        for (int m = 0; m < 4; ++m)
            #pragma unroll
            for (int n = 0; n < 4; ++n) {
                acc[m][n] = __builtin_amdgcn_mfma_f32_16x16x32_bf16(afh[m], bfh[n], acc[m][n], 0, 0, 0);
                acc[m][n] = __builtin_amdgcn_mfma_f32_16x16x32_bf16(afh[m], bfl[n], acc[m][n], 0, 0, 0);
                acc[m][n] = __builtin_amdgcn_mfma_f32_16x16x32_bf16(afl[m], bfh[n], acc[m][n], 0, 0, 0);
            }
        __syncthreads();
    }

    const int row0 = (mtile << 7) + wm * 64;
    const int col0 = (ntile << 7) + wn * 64;
    #pragma unroll
    for (int n = 0; n < 4; ++n) {
        const int col = col0 + n * 16 + r16;
        const float bc = bias[col];
        #pragma unroll
        for (int m = 0; m < 4; ++m)
            #pragma unroll
            for (int r = 0; r < 4; ++r) {
                const int row = row0 + m * 16 + kq * 4 + r;
                out[(size_t)row * 1024 + col] = acc[m][n][r] + bc;
            }
    }
}

// ---------------------------------------------------------------------------
// Qrel = Q_hi[65536x64] @ rel^T  -> bf16 QR[65536][272]
// ---------------------------------------------------------------------------
__global__ __launch_bounds__(256)
void qrel_gemm(const ushort_t* __restrict__ Qh, const ushort_t* __restrict__ relc,
               ushort_t* __restrict__ QR)
{
    __shared__ __align__(16) char lds[36864];
    const int tid = threadIdx.x;
    const int w = tid >> 6, l = tid & 63;
    const int r16 = l & 15, kq = l >> 4;
    const int blk = blockIdx.x;
    const int wb = (tid & 192) << 4;

    #pragma unroll
    for (int i = 0; i < 9; ++i)
        load_lds_16((const char*)relc + i * 4096 + tid * 16, lds + i * 4096 + wb);

    const int qrow = (blk << 6) + w * 16 + r16;
    bf16x8 ah[2];
    ah[0] = *reinterpret_cast<const bf16x8*>(Qh + (size_t)qrow * 64 + kq * 8);
    ah[1] = *reinterpret_cast<const bf16x8*>(Qh + (size_t)qrow * 64 + 32 + kq * 8);

    __syncthreads();

    f32x4 S[17] = {};
    const bf16x8* cB = reinterpret_cast<const bf16x8*>(lds);
    #pragma unroll
    for (int c = 0; c < 2; ++c) {
        #pragma unroll
        for (int n = 0; n < 17; ++n) {
            const bf16x8 bf = cB[(c * 4 + kq) * 272 + n * 16 + r16];
            S[n] = __builtin_amdgcn_mfma_f32_16x16x32_bf16(ah[c], bf, S[n], 0, 0, 0);
        }
    }

    const int qbase = (blk << 6) + w * 16 + kq * 4;
    #pragma unroll
    for (int n = 0; n < 17; ++n) {
        const int col = n * 16 + r16;
        #pragma unroll
        for (int r = 0; r < 4; ++r)
            QR[(size_t)(qbase + r) * QRST + col] = f2bf(S[n][r]);
    }
}

// ---------------------------------------------------------------------------
// MFMA flash attention v2. Block = 128 q-rows x one bh, 4 waves (32 q each,
// two 16-row A-blocks m=0,1). Grid 512 linear with XCD swizzle: all 8
// q-blocks of a bh land on one XCD (K/V L2-resident).
// P layout [q 128][68]: scalar writes uniform-2-way (free), b128 reads at
// the 8/bank floor.
// ---------------------------------------------------------------------------
__global__ __launch_bounds__(256, 2)
void attn_kernel(const ushort_t* __restrict__ Qhg, const ushort_t* __restrict__ Qlg,
                 const ushort_t* __restrict__ Kth, const ushort_t* __restrict__ Ktl,
                 const ushort_t* __restrict__ Vth, const ushort_t* __restrict__ QR,
                 ushort_t* __restrict__ AOh, ushort_t* __restrict__ AOl)
{
    __shared__ __align__(16) char lds[24576 + 128 * 68 * 4];
    float* P = (float*)(lds + 24576);            // [q 128][68]

    // XCD-aware decode: xcd = id&7 -> bh = (j>>3)*8 + xcd, qt = j&7
    const int id  = blockIdx.x;
    const int xcd = id & 7;
    const int j   = id >> 3;
    const int qt  = j & 7;
    const int bh  = ((j >> 3) << 3) | xcd;
    const int q0  = qt << 7;

    const int tid = threadIdx.x;
    const int w = tid >> 6;
    const int l = tid & 63;
    const int r16 = l & 15, kq = l >> 4;

    // --- Q fragments (2 m-blocks x 2 k-halves), hi/lo
    bf16x8 qh[2][2], ql[2][2];
    #pragma unroll
    for (int m = 0; m < 2; ++m) {
        const size_t qoff = (((size_t)bh << 10) + q0 + w * 32 + m * 16 + r16) * 64;
        #pragma unroll
        for (int c = 0; c < 2; ++c) {
            qh[m][c] = *reinterpret_cast<const bf16x8*>(Qhg + qoff + c * 32 + kq * 8);
            ql[m][c] = *reinterpret_cast<const bf16x8*>(Qlg + qoff + c * 32 + kq * 8);
        }
    }

    // --- clipped-bias end values per (m, r)
    float qr_lo[2][4], qr_hi[2][4];
    #pragma unroll
    for (int m = 0; m < 2; ++m)
        #pragma unroll
        for (int r = 0; r < 4; ++r) {
            const ushort_t* p = QR + (size_t)((bh << 10) + q0 + w * 32 + m * 16 + kq * 4 + r) * QRST;
            qr_lo[m][r] = bf2f(p[0]);
            qr_hi[m][r] = bf2f(p[256]);
        }

    float m_run[2][4] = {{-1e30f, -1e30f, -1e30f, -1e30f}, {-1e30f, -1e30f, -1e30f, -1e30f}};
    float l_run[2][4] = {};
    f32x4 accO[2][4] = {};

    const int wb = (tid & 192) << 4;

    for (int kt = 0; kt < S_LEN; kt += 64) {
        __syncthreads();   // staging buffer free

        // ---- stage Kh | Kl | Vt (8 KB each)
        {
            const size_t tbase = ((size_t)(bh * 16) + (kt >> 6)) * 8192;
            const char* gK = (const char*)Kth + tbase;
            const char* gL = (const char*)Ktl + tbase;
            const char* gV = (const char*)Vth + tbase;
            #pragma unroll
            for (int i = 0; i < 2; ++i) {
                load_lds_16(gK + i * 4096 + tid * 16, lds + i * 4096 + wb);
                load_lds_16(gL + i * 4096 + tid * 16, lds + 8192 + i * 4096 + wb);
                load_lds_16(gV + i * 4096 + tid * 16, lds + 16384 + i * 4096 + wb);
            }
        }

        // ---- rel-position bias (loads in flight across the staging barrier)
        float bias[2][4][4];   // [m][n][r]
        if (kt - q0 >= 256) {          // min d = kt-(q0+127) >= 128: fully hi-clipped
            #pragma unroll
            for (int m = 0; m < 2; ++m)
                #pragma unroll
                for (int n = 0; n < 4; ++n)
                    #pragma unroll
                    for (int r = 0; r < 4; ++r) bias[m][n][r] = qr_hi[m][r];
        } else if (q0 - kt >= 192) {   // max d = kt+63-q0 <= -128: fully lo-clipped
            #pragma unroll
            for (int m = 0; m < 2; ++m)
                #pragma unroll
                for (int n = 0; n < 4; ++n)
                    #pragma unroll
                    for (int r = 0; r < 4; ++r) bias[m][n][r] = qr_lo[m][r];
        } else {
            #pragma unroll
            for (int m = 0; m < 2; ++m) {
                const int qb = q0 + w * 32 + m * 16 + kq * 4;
                const int base_d = kt - qb + 128 + r16;
                #pragma unroll
                for (int r = 0; r < 4; ++r) {
                    const ushort_t* qrp = QR + (size_t)((bh << 10) + qb + r) * QRST;
                    #pragma unroll
                    for (int n = 0; n < 4; ++n) {
                        int dlt = base_d + n * 16 - r;
                        dlt = dlt < 0 ? 0 : (dlt > 256 ? 256 : dlt);
                        bias[m][n][r] = bf2f(qrp[dlt]);
                    }
                }
            }
        }

        __syncthreads();   // staging complete

        // ---- QK^T (3-pass split), both m-blocks share B-fragments
        f32x4 S[2][4] = {};
        const bf16x8* cK = reinterpret_cast<const bf16x8*>(lds);
        const bf16x8* cL = reinterpret_cast<const bf16x8*>(lds + 8192);
        #pragma unroll
        for (int c = 0; c < 2; ++c) {
            bf16x8 kh[4], kl[4];
            #pragma unroll
            for (int n = 0; n < 4; ++n) {
                const int idx = (c * 4 + kq) * 64 + n * 16 + r16;
                kh[n] = cK[idx]; kl[n] = cL[idx];
            }
            #pragma unroll
            for (int m = 0; m < 2; ++m)
                #pragma unroll
                for (int n = 0; n < 4; ++n) {
                    S[m][n] = __builtin_amdgcn_mfma_f32_16x16x32_bf16(qh[m][c], kh[n], S[m][n], 0, 0, 0);
                    S[m][n] = __builtin_amdgcn_mfma_f32_16x16x32_bf16(qh[m][c], kl[n], S[m][n], 0, 0, 0);
                    S[m][n] = __builtin_amdgcn_mfma_f32_16x16x32_bf16(ql[m][c], kh[n], S[m][n], 0, 0, 0);
                }
        }

        // ---- softmax per m-block
        #pragma unroll
        for (int m = 0; m < 2; ++m) {
            float pv[4][4];
            float tmax[4] = {-1e30f, -1e30f, -1e30f, -1e30f};
            #pragma unroll
            for (int n = 0; n < 4; ++n)
                #pragma unroll
                for (int r = 0; r < 4; ++r) {
                    const float s = S[m][n][r] + bias[m][n][r];
                    pv[n][r] = s;
                    tmax[r] = fmaxf(tmax[r], s);
                }
            #pragma unroll
            for (int r = 0; r < 4; ++r) {
                tmax[r] = fmaxf(tmax[r], __shfl_xor(tmax[r], 1));
                tmax[r] = fmaxf(tmax[r], __shfl_xor(tmax[r], 2));
                tmax[r] = fmaxf(tmax[r], __shfl_xor(tmax[r], 4));
                tmax[r] = fmaxf(tmax[r], __shfl_xor(tmax[r], 8));
            }
            float corr[4], psum[4] = {0.f, 0.f, 0.f, 0.f};
            #pragma unroll
            for (int r = 0; r < 4; ++r) {
                const float m_new = fmaxf(m_run[m][r], tmax[r]);
                corr[r] = __expf(m_run[m][r] - m_new);
                m_run[m][r] = m_new;
            }
            #pragma unroll
            for (int n = 0; n < 4; ++n)
                #pragma unroll
                for (int r = 0; r < 4; ++r) {
                    pv[n][r] = __expf(pv[n][r] - m_run[m][r]);
                    psum[r] += pv[n][r];
                }
            #pragma unroll
            for (int r = 0; r < 4; ++r) {
                psum[r] += __shfl_xor(psum[r], 1);
                psum[r] += __shfl_xor(psum[r], 2);
                psum[r] += __shfl_xor(psum[r], 4);
                psum[r] += __shfl_xor(psum[r], 8);
                l_run[m][r] = l_run[m][r] * corr[r] + psum[r];
            }
            #pragma unroll
            for (int n = 0; n < 4; ++n)
                #pragma unroll
                for (int r = 0; r < 4; ++r) accO[m][n][r] *= corr[r];

            // P[q][k]: q = w*32 + m*16 + kq*4 + r (block-local), k = n*16 + r16
            #pragma unroll
            for (int n = 0; n < 4; ++n)
                #pragma unroll
                for (int r = 0; r < 4; ++r)
                    P[(w * 32 + m * 16 + kq * 4 + r) * 68 + n * 16 + r16] = pv[n][r];
        }

        __syncthreads();   // P visibility (also keeps waves phase-locked)

        // ---- PV: pa via b128 reads along k
        const bf16x8* cV = reinterpret_cast<const bf16x8*>(lds + 16384);
        #pragma unroll
        for (int m = 0; m < 2; ++m) {
            const int prow = (w * 32 + m * 16 + r16) * 68;
            #pragma unroll
            for (int c = 0; c < 2; ++c) {
                float4 p0 = *reinterpret_cast<const float4*>(&P[prow + c * 32 + kq * 8]);
                float4 p1 = *reinterpret_cast<const float4*>(&P[prow + c * 32 + kq * 8 + 4]);
                bf16x8 pa;
                pa[0] = (short)f2bf(p0.x); pa[1] = (short)f2bf(p0.y);
                pa[2] = (short)f2bf(p0.z); pa[3] = (short)f2bf(p0.w);
                pa[4] = (short)f2bf(p1.x); pa[5] = (short)f2bf(p1.y);
                pa[6] = (short)f2bf(p1.z); pa[7] = (short)f2bf(p1.w);
                #pragma unroll
                for (int n = 0; n < 4; ++n) {
                    const bf16x8 vf = cV[(c * 4 + kq) * 64 + n * 16 + r16];
                    accO[m][n] = __builtin_amdgcn_mfma_f32_16x16x32_bf16(pa, vf, accO[m][n], 0, 0, 0);
                }
            }
        }
    }

    // ---- epilogue
    #pragma unroll
    for (int m = 0; m < 2; ++m) {
        float inv[4];
        #pragma unroll
        for (int r = 0; r < 4; ++r) inv[r] = 1.f / l_run[m][r];
        const int qs_base = q0 + w * 32 + m * 16 + kq * 4;
        #pragma unroll
        for (int n = 0; n < 4; ++n)
            #pragma unroll
            for (int r = 0; r < 4; ++r) {
                const float v = accO[m][n][r] * inv[r];
                const ushort_t h = f2bf(v);
                const ushort_t lo = f2bf(v - bf2f(h));
                const int r_g  = ((bh >> 4) << 10) + qs_base + r;
                const int kcol = ((bh & 15) << 6) + n * 16 + r16;
                const size_t idx = ((((size_t)(r_g >> 7) * 32 + (kcol >> 5)) * 4
                                    + ((kcol >> 3) & 3)) * 128 + (r_g & 127)) * 8 + (kcol & 7);
                AOh[idx] = h;
                AOl[idx] = lo;
            }
    }
}

// ---------------------------------------------------------------------------
extern "C" void kernel_launch(void* const* d_in, const int* in_sizes, int n_in,
                              void* d_out, int out_size, void* d_ws, size_t ws_size,
                              hipStream_t stream)
{
    const float* x   = (const float*)d_in[0];
    const float* Wq  = (const float*)d_in[1];
    const float* bq  = (const float*)d_in[2];
    const float* Wk  = (const float*)d_in[3];
    const float* bk  = (const float*)d_in[4];
    const float* Wv  = (const float*)d_in[5];
    const float* bv  = (const float*)d_in[6];
    const float* Wo  = (const float*)d_in[7];
    const float* bo  = (const float*)d_in[8];
    const float* rel = (const float*)d_in[9];
    float* out = (float*)d_out;

    char* W = (char*)d_ws;
    ushort_t* Qhb = (ushort_t*)(W);                 // 8 MB
    ushort_t* Qlb = (ushort_t*)(W + 8388608);       // 8 MB
    ushort_t* QR  = (ushort_t*)(W + 16777216);      // 35,651,584 B
    ushort_t* Kth = (ushort_t*)(W + 52428800);      // 8 MB
    ushort_t* Ktl = (ushort_t*)(W + 60817408);      // 8 MB
    ushort_t* Vth = (ushort_t*)(W + 69206016);      // 8 MB
    ushort_t* xh  = (ushort_t*)(W + 77594624);      // 8 MB
    ushort_t* xl  = (ushort_t*)(W + 85983232);      // 8 MB
    ushort_t* wAh = (ushort_t*)(W + 94371840);      // 6 MB  [Wq|Wk|Wv] hi
    ushort_t* wAl = (ushort_t*)(W + 100663296);     // 6 MB  [Wq|Wk|Wv] lo
    ushort_t* woh = (ushort_t*)(W + 106954752);     // 2 MB
    ushort_t* wol = (ushort_t*)(W + 109051904);     // 2 MB
    ushort_t* AOh = (ushort_t*)(W + 111149056);     // 8 MB
    ushort_t* AOl = (ushort_t*)(W + 119537664);     // 8 MB
    ushort_t* relc= (ushort_t*)(W + 127926272);     // 36,864 B (end 127,963,136)

    convert_split<<<2048, 256, 0, stream>>>(x,  xh,  xl);
    convert_split<<<512,  256, 0, stream>>>(Wq, wAh,            wAl);
    convert_split<<<512,  256, 0, stream>>>(Wk, wAh + 1048576,  wAl + 1048576);
    convert_split<<<512,  256, 0, stream>>>(Wv, wAh + 2097152,  wAl + 2097152);
    convert_split<<<512,  256, 0, stream>>>(Wo, woh, wol);
    rel_convert<<<9, 256, 0, stream>>>(rel, relc);

    gemm_qkv<<<dim3(24, 32), dim3(256), 0, stream>>>(
        xh, xl, wAh, wAl, bq, bk, bv, Qhb, Qlb, Kth, Ktl, Vth);

    qrel_gemm<<<1024, 256, 0, stream>>>(Qhb, relc, QR);

    attn_kernel<<<512, 256, 0, stream>>>(Qhb, Qlb, Kth, Ktl, Vth, QR, AOh, AOl);

    gemm_out<<<dim3(8, 32), dim3(256), 0, stream>>>(AOh, AOl, woh, wol, bo, out);
}

// Round 7
// 258.467 us; speedup vs baseline: 4.4245x; 1.2123x over previous
//
#include <hip/hip_runtime.h>
#include <math.h>

#define S_LEN 1024
#define NREL  257
#define QRST  272          // QR row stride (padded)

typedef _Float16 f16;
typedef __attribute__((ext_vector_type(8))) _Float16 f16x8;
typedef __attribute__((ext_vector_type(4))) float f32x4;

__device__ inline void load_lds_16(const void* g, void* l) {
    __builtin_amdgcn_global_load_lds(
        (const __attribute__((address_space(1))) void*)g,
        (__attribute__((address_space(3))) void*)l, 16, 0, 0);
}

// ---------------------------------------------------------------------------
// fp32 [R][1024] -> fp16 GEMM-operand tiles:
//   chunk t (16B = 8 f16): t = ((mtile*32 + ktile)*4 + kc)*128 + row128
// ---------------------------------------------------------------------------
__global__ __launch_bounds__(256)
void convert_f16(const float* __restrict__ src, f16* __restrict__ dst)
{
    const int t = blockIdx.x * 256 + threadIdx.x;
    const int row128 = t & 127;
    const int kc     = (t >> 7) & 3;
    const int ktile  = (t >> 9) & 31;
    const int mtile  = t >> 14;
    const float* s = src + ((size_t)(mtile * 128 + row128) * 1024) + ktile * 32 + kc * 8;
    float4 v0 = *reinterpret_cast<const float4*>(s);
    float4 v1 = *reinterpret_cast<const float4*>(s + 4);
    float v[8] = {v0.x, v0.y, v0.z, v0.w, v1.x, v1.y, v1.z, v1.w};
    union { f16 h[8]; int4 q; } H;
    #pragma unroll
    for (int i = 0; i < 8; ++i) H.h[i] = (f16)v[i];
    reinterpret_cast<int4*>(dst)[t] = H.q;
}

// All four weight matrices in one launch: grid (512, 4)
__global__ __launch_bounds__(256)
void convert_w(const float* __restrict__ Wq, const float* __restrict__ Wk,
               const float* __restrict__ Wv, const float* __restrict__ Wo,
               f16* __restrict__ wqkv, f16* __restrict__ wo)
{
    const int y = blockIdx.y;
    const float* src = (y == 0) ? Wq : (y == 1) ? Wk : (y == 2) ? Wv : Wo;
    f16* dst = (y < 3) ? (wqkv + (size_t)y * 1048576) : wo;
    const int t = blockIdx.x * 256 + threadIdx.x;   // 0..131071
    const int row128 = t & 127;
    const int kc     = (t >> 7) & 3;
    const int ktile  = (t >> 9) & 31;
    const int mtile  = t >> 14;
    const float* s = src + ((size_t)(mtile * 128 + row128) * 1024) + ktile * 32 + kc * 8;
    float4 v0 = *reinterpret_cast<const float4*>(s);
    float4 v1 = *reinterpret_cast<const float4*>(s + 4);
    float v[8] = {v0.x, v0.y, v0.z, v0.w, v1.x, v1.y, v1.z, v1.w};
    union { f16 h[8]; int4 q; } H;
    #pragma unroll
    for (int i = 0; i < 8; ++i) H.h[i] = (f16)v[i];
    reinterpret_cast<int4*>(dst)[t] = H.q;
}

// ---------------------------------------------------------------------------
// rel_emb fp32 [257][64] -> f16 chunk layout [8][272] chunks (zero-padded)
// ---------------------------------------------------------------------------
__global__ __launch_bounds__(256)
void rel_convert(const float* __restrict__ rel, f16* __restrict__ relc)
{
    const int t = blockIdx.x * 256 + threadIdx.x;   // 0..2303
    const int ck = t / 272, row = t % 272;
    union { f16 h[8]; int4 q; } H;
    #pragma unroll
    for (int i = 0; i < 8; ++i) H.h[i] = (f16)0.f;
    if (ck < 8 && row < NREL) {
        const float* s = rel + (size_t)row * 64 + ck * 8;
        float4 v0 = *reinterpret_cast<const float4*>(s);
        float4 v1 = *reinterpret_cast<const float4*>(s + 4);
        float v[8] = {v0.x, v0.y, v0.z, v0.w, v1.x, v1.y, v1.z, v1.w};
        #pragma unroll
        for (int i = 0; i < 8; ++i) H.h[i] = (f16)v[i];
    }
    reinterpret_cast<int4*>(relc)[t] = H.q;
}

// ---------------------------------------------------------------------------
// Merged Q/K/V projection GEMM, single-pass fp16 MFMA. 128x128 tile, BK=32,
// 4 waves. ntile 0..7 = Wq -> Q row-major f16 (scaled 0.125),
// 8..15 = Wk -> K attn-tiled f16, 16..23 = Wv -> V^T attn-tiled f16.
// LDS 32 KB (2 ops x 2 buf x 8 KB).
// ---------------------------------------------------------------------------
__global__ __launch_bounds__(256)
void gemm_qkv(const f16* __restrict__ Ah, const f16* __restrict__ Bh,
              const float* __restrict__ bq, const float* __restrict__ bk,
              const float* __restrict__ bv,
              f16* __restrict__ Qout, f16* __restrict__ Kt, f16* __restrict__ Vt)
{
    __shared__ __align__(16) f16 sm[2][2][4096];
    const int tid  = threadIdx.x;
    const int wave = tid >> 6, lane = tid & 63;
    const int wm = wave >> 1, wn = wave & 1;
    const int r16 = lane & 15, kq = lane >> 4;
    const int mtile = blockIdx.y;
    const int ntile = blockIdx.x;      // 0..23
    const int wb = (tid & ~63) << 3;   // f16-index of wave-uniform LDS base

    f32x4 acc[4][4] = {};

    auto stage = [&](int buf, int kt) {
        const f16* gA = Ah + ((size_t)(mtile * 32 + kt) << 12);
        const f16* gB = Bh + ((size_t)(ntile * 32 + kt) << 12);
        load_lds_16(gA + ((size_t)tid << 3),         &sm[buf][0][wb]);
        load_lds_16(gA + ((size_t)(tid + 256) << 3), &sm[buf][0][wb + 2048]);
        load_lds_16(gB + ((size_t)tid << 3),         &sm[buf][1][wb]);
        load_lds_16(gB + ((size_t)(tid + 256) << 3), &sm[buf][1][wb + 2048]);
    };

    stage(0, 0);
    __syncthreads();

    for (int kt = 0; kt < 32; ++kt) {
        const int cur = kt & 1;
        if (kt + 1 < 32) stage(cur ^ 1, kt + 1);

        const f16x8* pA = reinterpret_cast<const f16x8*>(sm[cur][0]);
        const f16x8* pB = reinterpret_cast<const f16x8*>(sm[cur][1]);

        f16x8 af[4], bf[4];
        #pragma unroll
        for (int m = 0; m < 4; ++m) af[m] = pA[kq * 128 + wm * 64 + m * 16 + r16];
        #pragma unroll
        for (int n = 0; n < 4; ++n) bf[n] = pB[kq * 128 + wn * 64 + n * 16 + r16];
        #pragma unroll
        for (int m = 0; m < 4; ++m)
            #pragma unroll
            for (int n = 0; n < 4; ++n)
                acc[m][n] = __builtin_amdgcn_mfma_f32_16x16x32_f16(af[m], bf[n], acc[m][n], 0, 0, 0);
        __syncthreads();
    }

    const int nsel = ntile >> 3;                       // 0=Q 1=K 2=V
    const float scale = (nsel == 0) ? 0.125f : 1.0f;
    const float* bp = (nsel == 0) ? bq : ((nsel == 1) ? bk : bv);
    const int row0 = (mtile << 7) + wm * 64;
    const int col0 = ((ntile & 7) << 7) + wn * 64;

    #pragma unroll
    for (int n = 0; n < 4; ++n) {
        const int col = col0 + n * 16 + r16;
        const float bc = bp[col];
        #pragma unroll
        for (int m = 0; m < 4; ++m) {
            #pragma unroll
            for (int r = 0; r < 4; ++r) {
                const int row = row0 + m * 16 + kq * 4 + r;
                const float val = (acc[m][n][r] + bc) * scale;
                const int b = row >> 10, s = row & 1023;
                const int nh = col >> 6, d = col & 63;
                if (nsel == 0) {            // Q row-major f16
                    Qout[((((size_t)(b * 16 + nh)) << 10 | (size_t)s) << 6) + d] = (f16)val;
                } else if (nsel == 1) {     // K attn-tiled f16
                    const size_t cidx = (((size_t)(b * 16 + nh) << 13) + ((s >> 6) << 9)
                                        + ((d >> 3) << 6) + (s & 63)) * 8 + (d & 7);
                    Kt[cidx] = (f16)val;
                } else {                    // V^T attn-tiled f16
                    const int kk = s & 63;
                    const size_t cidx = (((size_t)(b * 16 + nh) << 13) + ((s >> 6) << 9)
                                        + ((kk >> 3) << 6) + d) * 8 + (kk & 7);
                    Vt[cidx] = (f16)val;
                }
            }
        }
    }
}

// ---------------------------------------------------------------------------
// Final GEMM: out = AO @ Wo^T + bo (fp32 out). 128x64 tile, BK=32, 4 waves
// (2M x 2N, wave tile 64x32). LDS 24 KB -> better occupancy; grid 512.
// ---------------------------------------------------------------------------
__global__ __launch_bounds__(256)
void gemm_out(const f16* __restrict__ Ah, const f16* __restrict__ Bh,
              const float* __restrict__ bias, float* __restrict__ out)
{
    __shared__ __align__(16) f16 sm[2][6144];   // [buf][A 4096 | B 2048]
    const int tid  = threadIdx.x;
    const int wave = tid >> 6, lane = tid & 63;
    const int wm = wave >> 1, wn = wave & 1;
    const int r16 = lane & 15, kq = lane >> 4;
    const int mtile = blockIdx.y;
    const int ntile = blockIdx.x;      // 0..15 (64-col blocks)
    const int wb = (tid & ~63) << 3;

    f32x4 acc[4][2] = {};

    auto stage = [&](int buf, int kt) {
        const f16* gA = Ah + ((size_t)(mtile * 32 + kt) << 12);
        const f16* gB = Bh + ((size_t)((ntile >> 1) * 32 + kt) << 12) + ((ntile & 1) << 9);
        load_lds_16(gA + ((size_t)tid << 3),         &sm[buf][wb]);
        load_lds_16(gA + ((size_t)(tid + 256) << 3), &sm[buf][wb + 2048]);
        // B: thread t -> kc = t>>6, row64 = t&63
        load_lds_16(gB + (((size_t)(tid >> 6)) << 10) + ((size_t)(tid & 63) << 3),
                    &sm[buf][4096 + wb]);
    };

    stage(0, 0);
    __syncthreads();

    for (int kt = 0; kt < 32; ++kt) {
        const int cur = kt & 1;
        if (kt + 1 < 32) stage(cur ^ 1, kt + 1);

        const f16x8* pA = reinterpret_cast<const f16x8*>(&sm[cur][0]);
        const f16x8* pB = reinterpret_cast<const f16x8*>(&sm[cur][4096]);

        f16x8 af[4], bf[2];
        #pragma unroll
        for (int m = 0; m < 4; ++m) af[m] = pA[kq * 128 + wm * 64 + m * 16 + r16];
        #pragma unroll
        for (int n = 0; n < 2; ++n) bf[n] = pB[kq * 64 + wn * 32 + n * 16 + r16];
        #pragma unroll
        for (int m = 0; m < 4; ++m)
            #pragma unroll
            for (int n = 0; n < 2; ++n)
                acc[m][n] = __builtin_amdgcn_mfma_f32_16x16x32_f16(af[m], bf[n], acc[m][n], 0, 0, 0);
        __syncthreads();
    }

    const int row0 = (mtile << 7) + wm * 64;
    const int col0 = (ntile << 6) + wn * 32;
    #pragma unroll
    for (int n = 0; n < 2; ++n) {
        const int col = col0 + n * 16 + r16;
        const float bc = bias[col];
        #pragma unroll
        for (int m = 0; m < 4; ++m)
            #pragma unroll
            for (int r = 0; r < 4; ++r) {
                const int row = row0 + m * 16 + kq * 4 + r;
                out[(size_t)row * 1024 + col] = acc[m][n][r] + bc;
            }
    }
}

// ---------------------------------------------------------------------------
// Qrel = Q[65536x64] @ rel^T -> f16 QR[65536][272]
// ---------------------------------------------------------------------------
__global__ __launch_bounds__(256)
void qrel_gemm(const f16* __restrict__ Qf, const f16* __restrict__ relc,
               f16* __restrict__ QR)
{
    __shared__ __align__(16) char lds[36864];
    const int tid = threadIdx.x;
    const int w = tid >> 6, l = tid & 63;
    const int r16 = l & 15, kq = l >> 4;
    const int blk = blockIdx.x;
    const int wb = (tid & 192) << 4;

    #pragma unroll
    for (int i = 0; i < 9; ++i)
        load_lds_16((const char*)relc + i * 4096 + tid * 16, lds + i * 4096 + wb);

    const int qrow = (blk << 6) + w * 16 + r16;
    f16x8 ah[2];
    ah[0] = *reinterpret_cast<const f16x8*>(Qf + (size_t)qrow * 64 + kq * 8);
    ah[1] = *reinterpret_cast<const f16x8*>(Qf + (size_t)qrow * 64 + 32 + kq * 8);

    __syncthreads();

    f32x4 S[17] = {};
    const f16x8* cB = reinterpret_cast<const f16x8*>(lds);
    #pragma unroll
    for (int c = 0; c < 2; ++c) {
        #pragma unroll
        for (int n = 0; n < 17; ++n) {
            const f16x8 bf = cB[(c * 4 + kq) * 272 + n * 16 + r16];
            S[n] = __builtin_amdgcn_mfma_f32_16x16x32_f16(ah[c], bf, S[n], 0, 0, 0);
        }
    }

    const int qbase = (blk << 6) + w * 16 + kq * 4;
    #pragma unroll
    for (int n = 0; n < 17; ++n) {
        const int col = n * 16 + r16;
        #pragma unroll
        for (int r = 0; r < 4; ++r)
            QR[(size_t)(qbase + r) * QRST + col] = (f16)S[n][r];
    }
}

// ---------------------------------------------------------------------------
// fp16 MFMA flash attention. Block = 128 q-rows x one bh, 4 waves (32 q each).
// XCD-swizzled grid. K/V^T staged f16 (16 KB); P fp32 LDS [128][68].
// ---------------------------------------------------------------------------
__global__ __launch_bounds__(256, 2)
void attn_kernel(const f16* __restrict__ Qf, const f16* __restrict__ Kt,
                 const f16* __restrict__ Vt, const f16* __restrict__ QR,
                 f16* __restrict__ AO)
{
    __shared__ __align__(16) char lds[16384 + 128 * 68 * 4];
    float* P = (float*)(lds + 16384);            // [q 128][68]

    const int id  = blockIdx.x;
    const int xcd = id & 7;
    const int j   = id >> 3;
    const int qt  = j & 7;
    const int bh  = ((j >> 3) << 3) | xcd;
    const int q0  = qt << 7;

    const int tid = threadIdx.x;
    const int w = tid >> 6;
    const int l = tid & 63;
    const int r16 = l & 15, kq = l >> 4;

    // --- Q fragments (2 m-blocks x 2 k-halves)
    f16x8 qf[2][2];
    #pragma unroll
    for (int m = 0; m < 2; ++m) {
        const size_t qoff = (((size_t)bh << 10) + q0 + w * 32 + m * 16 + r16) * 64;
        #pragma unroll
        for (int c = 0; c < 2; ++c)
            qf[m][c] = *reinterpret_cast<const f16x8*>(Qf + qoff + c * 32 + kq * 8);
    }

    // --- clipped-bias end values per (m, r)
    float qr_lo[2][4], qr_hi[2][4];
    #pragma unroll
    for (int m = 0; m < 2; ++m)
        #pragma unroll
        for (int r = 0; r < 4; ++r) {
            const f16* p = QR + (size_t)((bh << 10) + q0 + w * 32 + m * 16 + kq * 4 + r) * QRST;
            qr_lo[m][r] = (float)p[0];
            qr_hi[m][r] = (float)p[256];
        }

    float m_run[2][4] = {{-1e30f, -1e30f, -1e30f, -1e30f}, {-1e30f, -1e30f, -1e30f, -1e30f}};
    float l_run[2][4] = {};
    f32x4 accO[2][4] = {};

    const int wb = (tid & 192) << 4;

    for (int kt = 0; kt < S_LEN; kt += 64) {
        __syncthreads();   // staging buffer free

        // ---- stage K | Vt (8 KB each)
        {
            const size_t tbase = ((size_t)(bh * 16) + (kt >> 6)) * 8192;
            const char* gK = (const char*)Kt + tbase;
            const char* gV = (const char*)Vt + tbase;
            #pragma unroll
            for (int i = 0; i < 2; ++i) {
                load_lds_16(gK + i * 4096 + tid * 16, lds + i * 4096 + wb);
                load_lds_16(gV + i * 4096 + tid * 16, lds + 8192 + i * 4096 + wb);
            }
        }

        // ---- rel-position bias (loads in flight across the staging barrier)
        float bias[2][4][4];   // [m][n][r]
        if (kt - q0 >= 256) {
            #pragma unroll
            for (int m = 0; m < 2; ++m)
                #pragma unroll
                for (int n = 0; n < 4; ++n)
                    #pragma unroll
                    for (int r = 0; r < 4; ++r) bias[m][n][r] = qr_hi[m][r];
        } else if (q0 - kt >= 192) {
            #pragma unroll
            for (int m = 0; m < 2; ++m)
                #pragma unroll
                for (int n = 0; n < 4; ++n)
                    #pragma unroll
                    for (int r = 0; r < 4; ++r) bias[m][n][r] = qr_lo[m][r];
        } else {
            #pragma unroll
            for (int m = 0; m < 2; ++m) {
                const int qb = q0 + w * 32 + m * 16 + kq * 4;
                const int base_d = kt - qb + 128 + r16;
                #pragma unroll
                for (int r = 0; r < 4; ++r) {
                    const f16* qrp = QR + (size_t)((bh << 10) + qb + r) * QRST;
                    #pragma unroll
                    for (int n = 0; n < 4; ++n) {
                        int dlt = base_d + n * 16 - r;
                        dlt = dlt < 0 ? 0 : (dlt > 256 ? 256 : dlt);
                        bias[m][n][r] = (float)qrp[dlt];
                    }
                }
            }
        }

        __syncthreads();   // staging complete

        // ---- QK^T (single-pass fp16)
        f32x4 S[2][4] = {};
        const f16x8* cK = reinterpret_cast<const f16x8*>(lds);
        #pragma unroll
        for (int c = 0; c < 2; ++c) {
            f16x8 kf[4];
            #pragma unroll
            for (int n = 0; n < 4; ++n)
                kf[n] = cK[(c * 4 + kq) * 64 + n * 16 + r16];
            #pragma unroll
            for (int m = 0; m < 2; ++m)
                #pragma unroll
                for (int n = 0; n < 4; ++n)
                    S[m][n] = __builtin_amdgcn_mfma_f32_16x16x32_f16(qf[m][c], kf[n], S[m][n], 0, 0, 0);
        }

        // ---- softmax per m-block
        #pragma unroll
        for (int m = 0; m < 2; ++m) {
            float pv[4][4];
            float tmax[4] = {-1e30f, -1e30f, -1e30f, -1e30f};
            #pragma unroll
            for (int n = 0; n < 4; ++n)
                #pragma unroll
                for (int r = 0; r < 4; ++r) {
                    const float s = S[m][n][r] + bias[m][n][r];
                    pv[n][r] = s;
                    tmax[r] = fmaxf(tmax[r], s);
                }
            #pragma unroll
            for (int r = 0; r < 4; ++r) {
                tmax[r] = fmaxf(tmax[r], __shfl_xor(tmax[r], 1));
                tmax[r] = fmaxf(tmax[r], __shfl_xor(tmax[r], 2));
                tmax[r] = fmaxf(tmax[r], __shfl_xor(tmax[r], 4));
                tmax[r] = fmaxf(tmax[r], __shfl_xor(tmax[r], 8));
            }
            float corr[4], psum[4] = {0.f, 0.f, 0.f, 0.f};
            #pragma unroll
            for (int r = 0; r < 4; ++r) {
                const float m_new = fmaxf(m_run[m][r], tmax[r]);
                corr[r] = __expf(m_run[m][r] - m_new);
                m_run[m][r] = m_new;
            }
            #pragma unroll
            for (int n = 0; n < 4; ++n)
                #pragma unroll
                for (int r = 0; r < 4; ++r) {
                    pv[n][r] = __expf(pv[n][r] - m_run[m][r]);
                    psum[r] += pv[n][r];
                }
            #pragma unroll
            for (int r = 0; r < 4; ++r) {
                psum[r] += __shfl_xor(psum[r], 1);
                psum[r] += __shfl_xor(psum[r], 2);
                psum[r] += __shfl_xor(psum[r], 4);
                psum[r] += __shfl_xor(psum[r], 8);
                l_run[m][r] = l_run[m][r] * corr[r] + psum[r];
            }
            #pragma unroll
            for (int n = 0; n < 4; ++n)
                #pragma unroll
                for (int r = 0; r < 4; ++r) accO[m][n][r] *= corr[r];

            #pragma unroll
            for (int n = 0; n < 4; ++n)
                #pragma unroll
                for (int r = 0; r < 4; ++r)
                    P[(w * 32 + m * 16 + kq * 4 + r) * 68 + n * 16 + r16] = pv[n][r];
        }

        __syncthreads();   // P visibility

        // ---- PV (fp16 P and V)
        const f16x8* cV = reinterpret_cast<const f16x8*>(lds + 8192);
        #pragma unroll
        for (int m = 0; m < 2; ++m) {
            const int prow = (w * 32 + m * 16 + r16) * 68;
            #pragma unroll
            for (int c = 0; c < 2; ++c) {
                float4 p0 = *reinterpret_cast<const float4*>(&P[prow + c * 32 + kq * 8]);
                float4 p1 = *reinterpret_cast<const float4*>(&P[prow + c * 32 + kq * 8 + 4]);
                f16x8 pa;
                pa[0] = (f16)p0.x; pa[1] = (f16)p0.y; pa[2] = (f16)p0.z; pa[3] = (f16)p0.w;
                pa[4] = (f16)p1.x; pa[5] = (f16)p1.y; pa[6] = (f16)p1.z; pa[7] = (f16)p1.w;
                #pragma unroll
                for (int n = 0; n < 4; ++n) {
                    const f16x8 vf = cV[(c * 4 + kq) * 64 + n * 16 + r16];
                    accO[m][n] = __builtin_amdgcn_mfma_f32_16x16x32_f16(pa, vf, accO[m][n], 0, 0, 0);
                }
            }
        }
    }

    // ---- epilogue: normalize, write f16 in final-GEMM tiled layout
    #pragma unroll
    for (int m = 0; m < 2; ++m) {
        float inv[4];
        #pragma unroll
        for (int r = 0; r < 4; ++r) inv[r] = 1.f / l_run[m][r];
        const int qs_base = q0 + w * 32 + m * 16 + kq * 4;
        #pragma unroll
        for (int n = 0; n < 4; ++n)
            #pragma unroll
            for (int r = 0; r < 4; ++r) {
                const float v = accO[m][n][r] * inv[r];
                const int r_g  = ((bh >> 4) << 10) + qs_base + r;
                const int kcol = ((bh & 15) << 6) + n * 16 + r16;
                const size_t idx = ((((size_t)(r_g >> 7) * 32 + (kcol >> 5)) * 4
                                    + ((kcol >> 3) & 3)) * 128 + (r_g & 127)) * 8 + (kcol & 7);
                AO[idx] = (f16)v;
            }
    }
}

// ---------------------------------------------------------------------------
extern "C" void kernel_launch(void* const* d_in, const int* in_sizes, int n_in,
                              void* d_out, int out_size, void* d_ws, size_t ws_size,
                              hipStream_t stream)
{
    const float* x   = (const float*)d_in[0];
    const float* Wq  = (const float*)d_in[1];
    const float* bq  = (const float*)d_in[2];
    const float* Wk  = (const float*)d_in[3];
    const float* bk  = (const float*)d_in[4];
    const float* Wv  = (const float*)d_in[5];
    const float* bv  = (const float*)d_in[6];
    const float* Wo  = (const float*)d_in[7];
    const float* bo  = (const float*)d_in[8];
    const float* rel = (const float*)d_in[9];
    float* out = (float*)d_out;

    char* W = (char*)d_ws;
    f16* Qf   = (f16*)(W);                 // 8 MB  row-major [bh][s][64]
    f16* QR   = (f16*)(W + 8388608);       // 35,651,584 B
    f16* Kt   = (f16*)(W + 44040192);      // 8 MB  attn-tiled
    f16* Vt   = (f16*)(W + 52428800);      // 8 MB  attn-tiled V^T
    f16* xt   = (f16*)(W + 60817408);      // 8 MB  x tiled
    f16* wqkv = (f16*)(W + 69206016);      // 6 MB  [Wq|Wk|Wv] tiled
    f16* wo   = (f16*)(W + 75497472);      // 2 MB  Wo tiled
    f16* AO   = (f16*)(W + 77594624);      // 8 MB  AO tiled
    f16* relc = (f16*)(W + 85983232);      // 36,864 B (end 86,020,096)

    convert_f16<<<2048, 256, 0, stream>>>(x, xt);
    convert_w<<<dim3(512, 4), 256, 0, stream>>>(Wq, Wk, Wv, Wo, wqkv, wo);
    rel_convert<<<9, 256, 0, stream>>>(rel, relc);

    gemm_qkv<<<dim3(24, 32), dim3(256), 0, stream>>>(
        xt, wqkv, bq, bk, bv, Qf, Kt, Vt);

    qrel_gemm<<<1024, 256, 0, stream>>>(Qf, relc, QR);

    attn_kernel<<<512, 256, 0, stream>>>(Qf, Kt, Vt, QR, AO);

    gemm_out<<<dim3(16, 32), dim3(256), 0, stream>>>(AO, wo, bo, out);
}

// Round 8
// 219.307 us; speedup vs baseline: 5.2146x; 1.1786x over previous
//
#include <hip/hip_runtime.h>
#include <math.h>

#define S_LEN 1024
#define NREL  257
#define QRST  272          // QR row stride (padded)

typedef _Float16 f16;
typedef __attribute__((ext_vector_type(8))) _Float16 f16x8;
typedef __attribute__((ext_vector_type(4))) float f32x4;

__device__ inline void load_lds_16(const void* g, void* l) {
    __builtin_amdgcn_global_load_lds(
        (const __attribute__((address_space(1))) void*)g,
        (__attribute__((address_space(3))) void*)l, 16, 0, 0);
}

// ---------------------------------------------------------------------------
// fp32 [R][1024] -> fp16 GEMM-operand tiles:
//   chunk t (16B = 8 f16): t = ((mtile*32 + ktile)*4 + kc)*128 + row128
// ---------------------------------------------------------------------------
__global__ __launch_bounds__(256)
void convert_f16(const float* __restrict__ src, f16* __restrict__ dst)
{
    const int t = blockIdx.x * 256 + threadIdx.x;
    const int row128 = t & 127;
    const int kc     = (t >> 7) & 3;
    const int ktile  = (t >> 9) & 31;
    const int mtile  = t >> 14;
    const float* s = src + ((size_t)(mtile * 128 + row128) * 1024) + ktile * 32 + kc * 8;
    float4 v0 = *reinterpret_cast<const float4*>(s);
    float4 v1 = *reinterpret_cast<const float4*>(s + 4);
    float v[8] = {v0.x, v0.y, v0.z, v0.w, v1.x, v1.y, v1.z, v1.w};
    union { f16 h[8]; int4 q; } H;
    #pragma unroll
    for (int i = 0; i < 8; ++i) H.h[i] = (f16)v[i];
    reinterpret_cast<int4*>(dst)[t] = H.q;
}

// All four weight matrices in one launch: grid (512, 4)
__global__ __launch_bounds__(256)
void convert_w(const float* __restrict__ Wq, const float* __restrict__ Wk,
               const float* __restrict__ Wv, const float* __restrict__ Wo,
               f16* __restrict__ wqkv, f16* __restrict__ wo)
{
    const int y = blockIdx.y;
    const float* src = (y == 0) ? Wq : (y == 1) ? Wk : (y == 2) ? Wv : Wo;
    f16* dst = (y < 3) ? (wqkv + (size_t)y * 1048576) : wo;
    const int t = blockIdx.x * 256 + threadIdx.x;   // 0..131071
    const int row128 = t & 127;
    const int kc     = (t >> 7) & 3;
    const int ktile  = (t >> 9) & 31;
    const int mtile  = t >> 14;
    const float* s = src + ((size_t)(mtile * 128 + row128) * 1024) + ktile * 32 + kc * 8;
    float4 v0 = *reinterpret_cast<const float4*>(s);
    float4 v1 = *reinterpret_cast<const float4*>(s + 4);
    float v[8] = {v0.x, v0.y, v0.z, v0.w, v1.x, v1.y, v1.z, v1.w};
    union { f16 h[8]; int4 q; } H;
    #pragma unroll
    for (int i = 0; i < 8; ++i) H.h[i] = (f16)v[i];
    reinterpret_cast<int4*>(dst)[t] = H.q;
}

// ---------------------------------------------------------------------------
// rel_emb fp32 [257][64] -> f16 chunk layout [8][272] chunks (zero-padded)
// ---------------------------------------------------------------------------
__global__ __launch_bounds__(256)
void rel_convert(const float* __restrict__ rel, f16* __restrict__ relc)
{
    const int t = blockIdx.x * 256 + threadIdx.x;   // 0..2303
    const int ck = t / 272, row = t % 272;
    union { f16 h[8]; int4 q; } H;
    #pragma unroll
    for (int i = 0; i < 8; ++i) H.h[i] = (f16)0.f;
    if (ck < 8 && row < NREL) {
        const float* s = rel + (size_t)row * 64 + ck * 8;
        float4 v0 = *reinterpret_cast<const float4*>(s);
        float4 v1 = *reinterpret_cast<const float4*>(s + 4);
        float v[8] = {v0.x, v0.y, v0.z, v0.w, v1.x, v1.y, v1.z, v1.w};
        #pragma unroll
        for (int i = 0; i < 8; ++i) H.h[i] = (f16)v[i];
    }
    reinterpret_cast<int4*>(relc)[t] = H.q;
}

// ---------------------------------------------------------------------------
// Merged Q/K/V projection GEMM, single-pass fp16 MFMA. 128x128 tile, BK=32,
// 4 waves. ntile 0..7 = Wq, 8..15 = Wk, 16..23 = Wv.
// ---------------------------------------------------------------------------
__global__ __launch_bounds__(256)
void gemm_qkv(const f16* __restrict__ Ah, const f16* __restrict__ Bh,
              const float* __restrict__ bq, const float* __restrict__ bk,
              const float* __restrict__ bv,
              f16* __restrict__ Qout, f16* __restrict__ Kt, f16* __restrict__ Vt)
{
    __shared__ __align__(16) f16 sm[2][2][4096];
    const int tid  = threadIdx.x;
    const int wave = tid >> 6, lane = tid & 63;
    const int wm = wave >> 1, wn = wave & 1;
    const int r16 = lane & 15, kq = lane >> 4;
    const int mtile = blockIdx.y;
    const int ntile = blockIdx.x;      // 0..23
    const int wb = (tid & ~63) << 3;

    f32x4 acc[4][4] = {};

    auto stage = [&](int buf, int kt) {
        const f16* gA = Ah + ((size_t)(mtile * 32 + kt) << 12);
        const f16* gB = Bh + ((size_t)(ntile * 32 + kt) << 12);
        load_lds_16(gA + ((size_t)tid << 3),         &sm[buf][0][wb]);
        load_lds_16(gA + ((size_t)(tid + 256) << 3), &sm[buf][0][wb + 2048]);
        load_lds_16(gB + ((size_t)tid << 3),         &sm[buf][1][wb]);
        load_lds_16(gB + ((size_t)(tid + 256) << 3), &sm[buf][1][wb + 2048]);
    };

    stage(0, 0);
    __syncthreads();

    for (int kt = 0; kt < 32; ++kt) {
        const int cur = kt & 1;
        if (kt + 1 < 32) stage(cur ^ 1, kt + 1);

        const f16x8* pA = reinterpret_cast<const f16x8*>(sm[cur][0]);
        const f16x8* pB = reinterpret_cast<const f16x8*>(sm[cur][1]);

        f16x8 af[4], bf[4];
        #pragma unroll
        for (int m = 0; m < 4; ++m) af[m] = pA[kq * 128 + wm * 64 + m * 16 + r16];
        #pragma unroll
        for (int n = 0; n < 4; ++n) bf[n] = pB[kq * 128 + wn * 64 + n * 16 + r16];
        #pragma unroll
        for (int m = 0; m < 4; ++m)
            #pragma unroll
            for (int n = 0; n < 4; ++n)
                acc[m][n] = __builtin_amdgcn_mfma_f32_16x16x32_f16(af[m], bf[n], acc[m][n], 0, 0, 0);
        __syncthreads();
    }

    const int nsel = ntile >> 3;                       // 0=Q 1=K 2=V
    const float scale = (nsel == 0) ? 0.125f : 1.0f;
    const float* bp = (nsel == 0) ? bq : ((nsel == 1) ? bk : bv);
    const int row0 = (mtile << 7) + wm * 64;
    const int col0 = ((ntile & 7) << 7) + wn * 64;

    #pragma unroll
    for (int n = 0; n < 4; ++n) {
        const int col = col0 + n * 16 + r16;
        const float bc = bp[col];
        #pragma unroll
        for (int m = 0; m < 4; ++m) {
            #pragma unroll
            for (int r = 0; r < 4; ++r) {
                const int row = row0 + m * 16 + kq * 4 + r;
                const float val = (acc[m][n][r] + bc) * scale;
                const int b = row >> 10, s = row & 1023;
                const int nh = col >> 6, d = col & 63;
                if (nsel == 0) {            // Q row-major f16
                    Qout[((((size_t)(b * 16 + nh)) << 10 | (size_t)s) << 6) + d] = (f16)val;
                } else if (nsel == 1) {     // K attn-tiled f16
                    const size_t cidx = (((size_t)(b * 16 + nh) << 13) + ((s >> 6) << 9)
                                        + ((d >> 3) << 6) + (s & 63)) * 8 + (d & 7);
                    Kt[cidx] = (f16)val;
                } else {                    // V^T attn-tiled f16
                    const int kk = s & 63;
                    const size_t cidx = (((size_t)(b * 16 + nh) << 13) + ((s >> 6) << 9)
                                        + ((kk >> 3) << 6) + d) * 8 + (kk & 7);
                    Vt[cidx] = (f16)val;
                }
            }
        }
    }
}

// ---------------------------------------------------------------------------
// Final GEMM: out = AO @ Wo^T + bo (fp32 out). 128x64 tile, BK=32, 4 waves.
// ---------------------------------------------------------------------------
__global__ __launch_bounds__(256)
void gemm_out(const f16* __restrict__ Ah, const f16* __restrict__ Bh,
              const float* __restrict__ bias, float* __restrict__ out)
{
    __shared__ __align__(16) f16 sm[2][6144];   // [buf][A 4096 | B 2048]
    const int tid  = threadIdx.x;
    const int wave = tid >> 6, lane = tid & 63;
    const int wm = wave >> 1, wn = wave & 1;
    const int r16 = lane & 15, kq = lane >> 4;
    const int mtile = blockIdx.y;
    const int ntile = blockIdx.x;      // 0..15 (64-col blocks)
    const int wb = (tid & ~63) << 3;

    f32x4 acc[4][2] = {};

    auto stage = [&](int buf, int kt) {
        const f16* gA = Ah + ((size_t)(mtile * 32 + kt) << 12);
        const f16* gB = Bh + ((size_t)((ntile >> 1) * 32 + kt) << 12) + ((ntile & 1) << 9);
        load_lds_16(gA + ((size_t)tid << 3),         &sm[buf][wb]);
        load_lds_16(gA + ((size_t)(tid + 256) << 3), &sm[buf][wb + 2048]);
        load_lds_16(gB + (((size_t)(tid >> 6)) << 10) + ((size_t)(tid & 63) << 3),
                    &sm[buf][4096 + wb]);
    };

    stage(0, 0);
    __syncthreads();

    for (int kt = 0; kt < 32; ++kt) {
        const int cur = kt & 1;
        if (kt + 1 < 32) stage(cur ^ 1, kt + 1);

        const f16x8* pA = reinterpret_cast<const f16x8*>(&sm[cur][0]);
        const f16x8* pB = reinterpret_cast<const f16x8*>(&sm[cur][4096]);

        f16x8 af[4], bf[2];
        #pragma unroll
        for (int m = 0; m < 4; ++m) af[m] = pA[kq * 128 + wm * 64 + m * 16 + r16];
        #pragma unroll
        for (int n = 0; n < 2; ++n) bf[n] = pB[kq * 64 + wn * 32 + n * 16 + r16];
        #pragma unroll
        for (int m = 0; m < 4; ++m)
            #pragma unroll
            for (int n = 0; n < 2; ++n)
                acc[m][n] = __builtin_amdgcn_mfma_f32_16x16x32_f16(af[m], bf[n], acc[m][n], 0, 0, 0);
        __syncthreads();
    }

    const int row0 = (mtile << 7) + wm * 64;
    const int col0 = (ntile << 6) + wn * 32;
    #pragma unroll
    for (int n = 0; n < 2; ++n) {
        const int col = col0 + n * 16 + r16;
        const float bc = bias[col];
        #pragma unroll
        for (int m = 0; m < 4; ++m)
            #pragma unroll
            for (int r = 0; r < 4; ++r) {
                const int row = row0 + m * 16 + kq * 4 + r;
                out[(size_t)row * 1024 + col] = acc[m][n][r] + bc;
            }
    }
}

// ---------------------------------------------------------------------------
// Qrel = Q[65536x64] @ rel^T -> f16 QR[65536][272]
// ---------------------------------------------------------------------------
__global__ __launch_bounds__(256)
void qrel_gemm(const f16* __restrict__ Qf, const f16* __restrict__ relc,
               f16* __restrict__ QR)
{
    __shared__ __align__(16) char lds[36864];
    const int tid = threadIdx.x;
    const int w = tid >> 6, l = tid & 63;
    const int r16 = l & 15, kq = l >> 4;
    const int blk = blockIdx.x;
    const int wb = (tid & 192) << 4;

    #pragma unroll
    for (int i = 0; i < 9; ++i)
        load_lds_16((const char*)relc + i * 4096 + tid * 16, lds + i * 4096 + wb);

    const int qrow = (blk << 6) + w * 16 + r16;
    f16x8 ah[2];
    ah[0] = *reinterpret_cast<const f16x8*>(Qf + (size_t)qrow * 64 + kq * 8);
    ah[1] = *reinterpret_cast<const f16x8*>(Qf + (size_t)qrow * 64 + 32 + kq * 8);

    __syncthreads();

    f32x4 S[17] = {};
    const f16x8* cB = reinterpret_cast<const f16x8*>(lds);
    #pragma unroll
    for (int c = 0; c < 2; ++c) {
        #pragma unroll
        for (int n = 0; n < 17; ++n) {
            const f16x8 bf = cB[(c * 4 + kq) * 272 + n * 16 + r16];
            S[n] = __builtin_amdgcn_mfma_f32_16x16x32_f16(ah[c], bf, S[n], 0, 0, 0);
        }
    }

    const int qbase = (blk << 6) + w * 16 + kq * 4;
    #pragma unroll
    for (int n = 0; n < 17; ++n) {
        const int col = n * 16 + r16;
        #pragma unroll
        for (int r = 0; r < 4; ++r)
            QR[(size_t)(qbase + r) * QRST + col] = (f16)S[n][r];
    }
}

// ---------------------------------------------------------------------------
// fp16 MFMA flash attention v3: double-buffered K/V staging (issue-early),
// pipelined bias gather, single barrier per k-iter, P wave-private f16 LDS,
// row-sum l_run via ones-column MFMA (no sum shuffles).
// Block = 128 q-rows x one bh, 4 waves; XCD-swizzled grid 512.
// LDS: kv dbuf 2x16KB + P f16 [128][72] = 50 KB.
// ---------------------------------------------------------------------------
__global__ __launch_bounds__(256, 2)
void attn_kernel(const f16* __restrict__ Qf, const f16* __restrict__ Kt,
                 const f16* __restrict__ Vt, const f16* __restrict__ QR,
                 f16* __restrict__ AO)
{
    __shared__ __align__(16) char lds[32768 + 128 * 72 * 2];
    f16* Pf = (f16*)(lds + 32768);               // [q 128][72]

    const int id  = blockIdx.x;
    const int xcd = id & 7;
    const int j   = id >> 3;
    const int qt  = j & 7;
    const int bh  = ((j >> 3) << 3) | xcd;
    const int q0  = qt << 7;

    const int tid = threadIdx.x;
    const int w = tid >> 6;
    const int l = tid & 63;
    const int r16 = l & 15, kq = l >> 4;
    const int wb = (tid & 192) << 4;

    // --- Q fragments (2 m-blocks x 2 k-halves)
    f16x8 qf[2][2];
    #pragma unroll
    for (int m = 0; m < 2; ++m) {
        const size_t qoff = (((size_t)bh << 10) + q0 + w * 32 + m * 16 + r16) * 64;
        #pragma unroll
        for (int c = 0; c < 2; ++c)
            qf[m][c] = *reinterpret_cast<const f16x8*>(Qf + qoff + c * 32 + kq * 8);
    }

    // --- clipped-bias end values per (m, r)
    float qr_lo[2][4], qr_hi[2][4];
    #pragma unroll
    for (int m = 0; m < 2; ++m)
        #pragma unroll
        for (int r = 0; r < 4; ++r) {
            const f16* p = QR + (size_t)((bh << 10) + q0 + w * 32 + m * 16 + kq * 4 + r) * QRST;
            qr_lo[m][r] = (float)p[0];
            qr_hi[m][r] = (float)p[256];
        }

    float m_run[2][4] = {{-1e30f, -1e30f, -1e30f, -1e30f}, {-1e30f, -1e30f, -1e30f, -1e30f}};
    f32x4 accO[2][4] = {};
    f32x4 acc_l[2] = {};

    auto stage = [&](int buf, int t) {
        const size_t tbase = ((size_t)(bh * 16) + t) * 8192;
        const char* gK = (const char*)Kt + tbase;
        const char* gV = (const char*)Vt + tbase;
        #pragma unroll
        for (int i = 0; i < 2; ++i) {
            load_lds_16(gK + i * 4096 + tid * 16, lds + buf * 16384 + i * 4096 + wb);
            load_lds_16(gV + i * 4096 + tid * 16, lds + buf * 16384 + 8192 + i * 4096 + wb);
        }
    };

    auto gather = [&](int t, float (&bb)[2][4][4]) {
        const int ktv = t << 6;
        if (ktv - q0 >= 256) {
            #pragma unroll
            for (int m = 0; m < 2; ++m)
                #pragma unroll
                for (int n = 0; n < 4; ++n)
                    #pragma unroll
                    for (int r = 0; r < 4; ++r) bb[m][n][r] = qr_hi[m][r];
        } else if (q0 - ktv >= 192) {
            #pragma unroll
            for (int m = 0; m < 2; ++m)
                #pragma unroll
                for (int n = 0; n < 4; ++n)
                    #pragma unroll
                    for (int r = 0; r < 4; ++r) bb[m][n][r] = qr_lo[m][r];
        } else {
            #pragma unroll
            for (int m = 0; m < 2; ++m) {
                const int qb = q0 + w * 32 + m * 16 + kq * 4;
                const int base_d = ktv - qb + 128 + r16;
                #pragma unroll
                for (int r = 0; r < 4; ++r) {
                    const f16* qrp = QR + (size_t)((bh << 10) + qb + r) * QRST;
                    #pragma unroll
                    for (int n = 0; n < 4; ++n) {
                        int dlt = base_d + n * 16 - r;
                        dlt = dlt < 0 ? 0 : (dlt > 256 ? 256 : dlt);
                        bb[m][n][r] = (float)qrp[dlt];
                    }
                }
            }
        }
    };

    float biasc[2][4][4];
    stage(0, 0);
    gather(0, biasc);
    __syncthreads();   // stage(0) landed

    const f16x8 ones = {(f16)1.f, (f16)1.f, (f16)1.f, (f16)1.f,
                        (f16)1.f, (f16)1.f, (f16)1.f, (f16)1.f};

    for (int t = 0; t < 16; ++t) {
        const int cur = t & 1;
        float nb[2][4][4];
        if (t + 1 < 16) {
            stage(cur ^ 1, t + 1);     // issue early; lands by next iter's barrier
            gather(t + 1, nb);         // loads in flight under this iter's compute
        }

        // ---- QK^T (single-pass fp16)
        f32x4 S[2][4] = {};
        const f16x8* cK = reinterpret_cast<const f16x8*>(lds + cur * 16384);
        #pragma unroll
        for (int c = 0; c < 2; ++c) {
            f16x8 kf[4];
            #pragma unroll
            for (int n = 0; n < 4; ++n)
                kf[n] = cK[(c * 4 + kq) * 64 + n * 16 + r16];
            #pragma unroll
            for (int m = 0; m < 2; ++m)
                #pragma unroll
                for (int n = 0; n < 4; ++n)
                    S[m][n] = __builtin_amdgcn_mfma_f32_16x16x32_f16(qf[m][c], kf[n], S[m][n], 0, 0, 0);
        }

        // ---- softmax per m-block (max shuffles only; sums via ones-MFMA)
        #pragma unroll
        for (int m = 0; m < 2; ++m) {
            float pv[4][4];
            float tmax[4] = {-1e30f, -1e30f, -1e30f, -1e30f};
            #pragma unroll
            for (int n = 0; n < 4; ++n)
                #pragma unroll
                for (int r = 0; r < 4; ++r) {
                    const float s = S[m][n][r] + biasc[m][n][r];
                    pv[n][r] = s;
                    tmax[r] = fmaxf(tmax[r], s);
                }
            #pragma unroll
            for (int r = 0; r < 4; ++r) {
                tmax[r] = fmaxf(tmax[r], __shfl_xor(tmax[r], 1));
                tmax[r] = fmaxf(tmax[r], __shfl_xor(tmax[r], 2));
                tmax[r] = fmaxf(tmax[r], __shfl_xor(tmax[r], 4));
                tmax[r] = fmaxf(tmax[r], __shfl_xor(tmax[r], 8));
            }
            float corr[4];
            #pragma unroll
            for (int r = 0; r < 4; ++r) {
                const float m_new = fmaxf(m_run[m][r], tmax[r]);
                corr[r] = __expf(m_run[m][r] - m_new);
                m_run[m][r] = m_new;
            }
            #pragma unroll
            for (int n = 0; n < 4; ++n)
                #pragma unroll
                for (int r = 0; r < 4; ++r)
                    pv[n][r] = __expf(pv[n][r] - m_run[m][r]);
            #pragma unroll
            for (int n = 0; n < 4; ++n)
                #pragma unroll
                for (int r = 0; r < 4; ++r) accO[m][n][r] *= corr[r];
            #pragma unroll
            for (int r = 0; r < 4; ++r) acc_l[m][r] *= corr[r];

            // P f16 write (wave-private rows w*32..w*32+31)
            #pragma unroll
            for (int n = 0; n < 4; ++n)
                #pragma unroll
                for (int r = 0; r < 4; ++r)
                    Pf[(w * 32 + m * 16 + kq * 4 + r) * 72 + n * 16 + r16] = (f16)pv[n][r];
        }

        // ---- PV (no barrier: P rows are wave-private; lgkmcnt ordering suffices)
        const f16x8* cV = reinterpret_cast<const f16x8*>(lds + cur * 16384 + 8192);
        #pragma unroll
        for (int m = 0; m < 2; ++m) {
            const int prow = (w * 32 + m * 16 + r16) * 72;
            #pragma unroll
            for (int c = 0; c < 2; ++c) {
                const f16x8 pa = *reinterpret_cast<const f16x8*>(&Pf[prow + c * 32 + kq * 8]);
                #pragma unroll
                for (int n = 0; n < 4; ++n) {
                    const f16x8 vf = cV[(c * 4 + kq) * 64 + n * 16 + r16];
                    accO[m][n] = __builtin_amdgcn_mfma_f32_16x16x32_f16(pa, vf, accO[m][n], 0, 0, 0);
                }
                acc_l[m] = __builtin_amdgcn_mfma_f32_16x16x32_f16(pa, ones, acc_l[m], 0, 0, 0);
            }
        }

        __syncthreads();   // stage(t+1) landed; kv[cur] reads done block-wide

        if (t + 1 < 16) {
            #pragma unroll
            for (int m = 0; m < 2; ++m)
                #pragma unroll
                for (int n = 0; n < 4; ++n)
                    #pragma unroll
                    for (int r = 0; r < 4; ++r) biasc[m][n][r] = nb[m][n][r];
        }
    }

    // ---- epilogue: normalize, write f16 in final-GEMM tiled layout
    #pragma unroll
    for (int m = 0; m < 2; ++m) {
        float inv[4];
        #pragma unroll
        for (int r = 0; r < 4; ++r) inv[r] = 1.f / acc_l[m][r];
        const int qs_base = q0 + w * 32 + m * 16 + kq * 4;
        #pragma unroll
        for (int n = 0; n < 4; ++n)
            #pragma unroll
            for (int r = 0; r < 4; ++r) {
                const float v = accO[m][n][r] * inv[r];
                const int r_g  = ((bh >> 4) << 10) + qs_base + r;
                const int kcol = ((bh & 15) << 6) + n * 16 + r16;
                const size_t idx = ((((size_t)(r_g >> 7) * 32 + (kcol >> 5)) * 4
                                    + ((kcol >> 3) & 3)) * 128 + (r_g & 127)) * 8 + (kcol & 7);
                AO[idx] = (f16)v;
            }
    }
}

// ---------------------------------------------------------------------------
extern "C" void kernel_launch(void* const* d_in, const int* in_sizes, int n_in,
                              void* d_out, int out_size, void* d_ws, size_t ws_size,
                              hipStream_t stream)
{
    const float* x   = (const float*)d_in[0];
    const float* Wq  = (const float*)d_in[1];
    const float* bq  = (const float*)d_in[2];
    const float* Wk  = (const float*)d_in[3];
    const float* bk  = (const float*)d_in[4];
    const float* Wv  = (const float*)d_in[5];
    const float* bv  = (const float*)d_in[6];
    const float* Wo  = (const float*)d_in[7];
    const float* bo  = (const float*)d_in[8];
    const float* rel = (const float*)d_in[9];
    float* out = (float*)d_out;

    char* W = (char*)d_ws;
    f16* Qf   = (f16*)(W);                 // 8 MB  row-major [bh][s][64]
    f16* QR   = (f16*)(W + 8388608);       // 35,651,584 B
    f16* Kt   = (f16*)(W + 44040192);      // 8 MB  attn-tiled
    f16* Vt   = (f16*)(W + 52428800);      // 8 MB  attn-tiled V^T
    f16* xt   = (f16*)(W + 60817408);      // 8 MB  x tiled
    f16* wqkv = (f16*)(W + 69206016);      // 6 MB  [Wq|Wk|Wv] tiled
    f16* wo   = (f16*)(W + 75497472);      // 2 MB  Wo tiled
    f16* AO   = (f16*)(W + 77594624);      // 8 MB  AO tiled
    f16* relc = (f16*)(W + 85983232);      // 36,864 B (end 86,020,096)

    convert_f16<<<2048, 256, 0, stream>>>(x, xt);
    convert_w<<<dim3(512, 4), 256, 0, stream>>>(Wq, Wk, Wv, Wo, wqkv, wo);
    rel_convert<<<9, 256, 0, stream>>>(rel, relc);

    gemm_qkv<<<dim3(24, 32), dim3(256), 0, stream>>>(
        xt, wqkv, bq, bk, bv, Qf, Kt, Vt);

    qrel_gemm<<<1024, 256, 0, stream>>>(Qf, relc, QR);

    attn_kernel<<<512, 256, 0, stream>>>(Qf, Kt, Vt, QR, AO);

    gemm_out<<<dim3(16, 32), dim3(256), 0, stream>>>(AO, wo, bo, out);
}